// Round 2
// baseline (2412.719 us; speedup 1.0000x reference)
//
#include <hip/hip_runtime.h>
#include <hip/hip_bf16.h>
#include <cstdint>
#include <cstddef>

#define D_MODEL   1024
#define D_INNER   2048
#define D_STATE   64
#define HEADDIM   128
#define NHEADS    16
#define D_CONV    4
#define CHUNK     256
#define D_IN_PROJ 4240     // 2*D_INNER + 2*D_STATE + NHEADS
#define CONV_DIM  2176     // D_INNER + 2*D_STATE
#define NB        2
#define LEN       4096
#define NC        16       // LEN / CHUNK
#define MROWS     (NB*LEN) // 8192

typedef __hip_bfloat16 bf16;

__device__ __forceinline__ float fsilu(float x){ return x / (1.f + __expf(-x)); }
__device__ __forceinline__ float toF(float x){ return x; }
__device__ __forceinline__ float toF(bf16 x){ return __bfloat162float(x); }
__device__ __forceinline__ void storeF(float* p, float v){ *p = v; }
__device__ __forceinline__ void storeF(bf16* p, float v){ *p = __float2bfloat16(v); }

// ---------------------------------------------------------------------------
// Generic tiled GEMM (both operands K-major), fp32 accumulate:
//   C[m,n] (+)= [exp(rs[m])] * sum_k A[m,k]*B[n,k]
// 64x64 tile, 256 threads, 4x4 per-thread microtile, TK=16.
// ---------------------------------------------------------------------------
template<typename TA, typename TB, typename TC, bool ACCUM, bool ROWSCALE_EXP>
__device__ __forceinline__ void gemm_body(
    const TA* __restrict__ A, int lda,
    const TB* __restrict__ B, int ldb,
    TC* __restrict__ C, int ldc,
    int M, int N, int K,
    const float* __restrict__ rs,
    int mt, int nt)
{
  __shared__ float As[16][68];
  __shared__ float Bs[16][68];
  const int tid = threadIdx.x;
  const int tx = tid & 15, ty = tid >> 4;
  const int m0 = mt*64, n0 = nt*64;
  float acc[4][4] = {};
  for (int k0 = 0; k0 < K; k0 += 16) {
    #pragma unroll
    for (int i = 0; i < 4; i++) {
      int e = tid + i*256;
      int k = e & 15, m = e >> 4;     // consecutive tid -> consecutive k (coalesced)
      int gm = m0 + m;
      As[k][m] = (gm < M) ? toF(A[(size_t)gm*lda + (k0+k)]) : 0.f;
      int gn = n0 + m;
      Bs[k][m] = (gn < N) ? toF(B[(size_t)gn*ldb + (k0+k)]) : 0.f;
    }
    __syncthreads();
    #pragma unroll
    for (int kk = 0; kk < 16; kk++) {
      float a[4], b[4];
      #pragma unroll
      for (int i=0;i<4;i++) a[i] = As[kk][ty*4+i];
      #pragma unroll
      for (int j=0;j<4;j++) b[j] = Bs[kk][tx*4+j];
      #pragma unroll
      for (int i=0;i<4;i++)
        #pragma unroll
        for (int j=0;j<4;j++)
          acc[i][j] += a[i]*b[j];
    }
    __syncthreads();
  }
  #pragma unroll
  for (int i=0;i<4;i++){
    int gm = m0 + ty*4 + i;
    if (gm >= M) continue;
    float sc = 1.f;
    if (ROWSCALE_EXP) sc = __expf(rs[gm]);
    #pragma unroll
    for (int j=0;j<4;j++){
      int gn = n0 + tx*4 + j;
      if (gn >= N) continue;
      size_t idx = (size_t)gm*ldc + gn;
      float v = acc[i][j]*sc;
      float old = ACCUM ? toF(C[idx]) : 0.f;
      storeF(&C[idx], v + old);
    }
  }
}

// zxbct = u @ in_proj_w^T   (8192 x 4240, K=1024) -> bf16
__global__ __launch_bounds__(256) void k_gemm_inproj(
    const float* __restrict__ u, const float* __restrict__ W, bf16* __restrict__ out){
  gemm_body<float,float,bf16,false,false>(u, D_MODEL, W, D_MODEL, out, D_IN_PROJ,
                         MROWS, D_IN_PROJ, D_MODEL, nullptr, blockIdx.x, blockIdx.y);
}

// out = y @ out_proj_w^T    (8192 x 1024, K=2048) -> fp32
__global__ __launch_bounds__(256) void k_gemm_outproj(
    const float* __restrict__ y, const float* __restrict__ W, float* __restrict__ out){
  gemm_body<float,float,float,false,false>(y, D_INNER, W, D_INNER, out, D_MODEL,
                         MROWS, D_MODEL, D_INNER, nullptr, blockIdx.x, blockIdx.y);
}

// S[z][q,k] = Cc[q,:] . Bc[k,:]   per chunk z = b*NC + c   (256x256, K=64)
__global__ __launch_bounds__(256) void k_gemm_scores(
    const bf16* __restrict__ xbc, float* __restrict__ S){
  int z = blockIdx.z;
  const bf16* Cc = xbc + (size_t)z*CHUNK*CONV_DIM + (D_INNER + D_STATE);
  const bf16* Bc = xbc + (size_t)z*CHUNK*CONV_DIM + D_INNER;
  gemm_body<bf16,bf16,float,false,false>(Cc, CONV_DIM, Bc, CONV_DIM,
                         S + (size_t)z*CHUNK*CHUNK, CHUNK,
                         CHUNK, CHUNK, D_STATE, nullptr, blockIdx.x, blockIdx.y);
}

// y[q, h*128+p] += exp(acum[q]) * sum_n C[q,n]*prev[h][p,n]   (256x128, K=64)
__global__ __launch_bounds__(256) void k_gemm_yoff(
    const bf16* __restrict__ xbc, const float* __restrict__ prev,
    const float* __restrict__ acum_t, float* __restrict__ y){
  int bid = blockIdx.z;
  int h = bid & 15, c = (bid>>4) & 15, b = bid >> 8;
  int z = b*NC + c;
  const bf16* Aop = xbc + (size_t)z*CHUNK*CONV_DIM + (D_INNER + D_STATE); // Cm slice
  const float* Bop = prev + (size_t)bid*HEADDIM*D_STATE;                  // [p][n]
  float* Cout = y + (size_t)z*CHUNK*D_INNER + h*HEADDIM;
  const float* rs = acum_t + ((size_t)(b*NHEADS + h))*LEN + c*CHUNK;
  gemm_body<bf16,float,float,true,true>(Aop, CONV_DIM, Bop, D_STATE, Cout, D_INNER,
                       CHUNK, HEADDIM, D_STATE, rs, blockIdx.x, blockIdx.y);
}

// ---------------------------------------------------------------------------
// dt = softplus(dt_raw + dt_bias); a = dt*A; inclusive cumsum over chunk.
// grid: 512 blocks (b,c,h), 256 threads (q)
// ---------------------------------------------------------------------------
__global__ __launch_bounds__(256) void k_dt(
    const bf16* __restrict__ zxbct, const float* __restrict__ dt_bias,
    const float* __restrict__ A_log, float* __restrict__ dt_t,
    float* __restrict__ acum_t, float* __restrict__ cd_t){
  int bid = blockIdx.x;
  int h = bid & 15, c = (bid>>4)&15, b = bid>>8;
  int q = threadIdx.x;
  size_t m = (size_t)(b*NC + c)*CHUNK + q;
  float x = toF(zxbct[m*D_IN_PROJ + (D_INNER + CONV_DIM) + h]) + dt_bias[h];
  float dtv = (x > 20.f) ? x : log1pf(__expf(x));
  float Ah = -__expf(A_log[h]);
  float a = dtv * Ah;
  __shared__ float sb[CHUNK];
  sb[q] = a;
  __syncthreads();
  #pragma unroll
  for (int off=1; off<CHUNK; off<<=1){
    float t = (q >= off) ? sb[q-off] : 0.f;
    __syncthreads();
    sb[q] += t;
    __syncthreads();
  }
  float ac = sb[q];
  size_t o = ((size_t)(b*NHEADS+h))*LEN + c*CHUNK + q;
  dt_t[o]   = dtv;
  acum_t[o] = ac;
  if (q == CHUNK-1) cd_t[(b*NHEADS+h)*NC + c] = __expf(ac);
}

// ---------------------------------------------------------------------------
// Depthwise causal conv (4 taps) + SiLU.  One thread per (m, ch).
// ---------------------------------------------------------------------------
__global__ __launch_bounds__(256) void k_conv(
    const bf16* __restrict__ zxbct, const float* __restrict__ conv_w,
    const float* __restrict__ conv_b, bf16* __restrict__ xbc){
  int idx = blockIdx.x*256 + threadIdx.x;
  int ch = idx % CONV_DIM;
  int m  = idx / CONV_DIM;
  int l  = m & (LEN-1);
  float acc = conv_b[ch];
  #pragma unroll
  for (int w=0; w<D_CONV; w++){
    int lw = l - (D_CONV-1) + w;
    if (lw >= 0)
      acc += toF(zxbct[((size_t)(m - (D_CONV-1) + w))*D_IN_PROJ + D_INNER + ch]) * conv_w[ch*D_CONV + w];
  }
  storeF(&xbc[(size_t)idx], fsilu(acc));
}

// ---------------------------------------------------------------------------
// y_diag[q,p] = sum_{k<=q} S[q,k]*exp(acum[q]-acum[k])*dt[k]*x[k,p]  (+ x*Dp)
// grid (2 qtiles, 512 (b,c,h)); 256 threads, 8x8 microtile over 128q x 128p
// ---------------------------------------------------------------------------
__global__ __launch_bounds__(256) void k_ydiag(
    const bf16* __restrict__ xbc, const float* __restrict__ S,
    const float* __restrict__ acum_t, const float* __restrict__ dt_t,
    const float* __restrict__ Dp, float* __restrict__ y){
  int qt = blockIdx.x;
  int bid = blockIdx.y;
  int h = bid & 15, c = (bid>>4)&15, b = bid>>8;
  const int q0 = qt*128;
  int tid = threadIdx.x; int tx = tid & 15, ty = tid >> 4;
  __shared__ float xs[32][132];
  __shared__ float Ss[32][132];
  __shared__ float aks[32], dks[32];
  const float* acum = acum_t + ((size_t)(b*NHEADS+h))*LEN + c*CHUNK;
  const float* dtc  = dt_t   + ((size_t)(b*NHEADS+h))*LEN + c*CHUNK;
  const float* Sbc  = S + ((size_t)(b*NC+c))*CHUNK*CHUNK;
  size_t xrowbase = ((size_t)(b*NC + c))*CHUNK*CONV_DIM + (size_t)h*HEADDIM;
  float accq[8];
  #pragma unroll
  for (int i=0;i<8;i++){ accq[i] = acum[q0 + ty*8 + i]; }
  float acc[8][8] = {};
  const int kmax = q0 + 128;
  for (int k0 = 0; k0 < kmax; k0 += 32) {
    #pragma unroll
    for (int i=0;i<16;i++){            // x tile: 32k x 128p
      int e = tid + i*256;
      int p = e & 127, kk = e >> 7;
      xs[kk][p] = toF(xbc[xrowbase + (size_t)(k0+kk)*CONV_DIM + p]);
    }
    #pragma unroll
    for (int i=0;i<16;i++){            // S tile: 128q x 32k, stored [k][q]
      int e = tid + i*256;
      int kk = e & 31, qq = e >> 5;
      Ss[kk][qq] = Sbc[(size_t)(q0+qq)*CHUNK + k0 + kk];
    }
    if (tid < 32) { aks[tid] = acum[k0+tid]; dks[tid] = dtc[k0+tid]; }
    __syncthreads();
    for (int kk=0; kk<32; kk++) {
      int k = k0 + kk;
      float ak = aks[kk], dk = dks[kk];
      float coef[8];
      #pragma unroll
      for (int i=0;i<8;i++){
        int q = q0 + ty*8 + i;
        float cf = Ss[kk][ty*8+i] * __expf(accq[i]-ak) * dk;
        coef[i] = (k <= q) ? cf : 0.f;   // mask selects 0 even if exp overflowed
      }
      #pragma unroll
      for (int j=0;j<8;j++){
        float xv = xs[kk][tx*8+j];
        #pragma unroll
        for (int i=0;i<8;i++) acc[i][j] += coef[i]*xv;
      }
    }
    __syncthreads();
  }
  float dph = Dp[h];
  size_t yrow = ((size_t)(b*NC + c))*CHUNK*D_INNER + (size_t)h*HEADDIM;
  #pragma unroll
  for (int i=0;i<8;i++){
    int q = q0 + ty*8 + i;
    #pragma unroll
    for (int j=0;j<8;j++){
      int p = tx*8 + j;
      float xv = toF(xbc[xrowbase + (size_t)q*CONV_DIM + p]);
      y[yrow + (size_t)q*D_INNER + p] = acc[i][j] + xv*dph;
    }
  }
}

// ---------------------------------------------------------------------------
// states[b,c,h][p,n] = sum_q dt[q]*exp(acum[255]-acum[q]) * x[q,p] * B[q,n]
// grid 512 (b,c,h), 256 threads: thread -> (p = tid>>1, n-half = tid&1)
// ---------------------------------------------------------------------------
__global__ __launch_bounds__(256) void k_states(
    const bf16* __restrict__ xbc, const float* __restrict__ acum_t,
    const float* __restrict__ dt_t, float* __restrict__ states){
  int bid = blockIdx.x;
  int h = bid & 15, c = (bid>>4)&15, b = bid>>8;
  int tid = threadIdx.x;
  __shared__ float wv[CHUNK];
  __shared__ float Bs[64][65];
  __shared__ float xs[64][128];
  const float* ac  = acum_t + ((size_t)(b*NHEADS+h))*LEN + c*CHUNK;
  const float* dtc = dt_t   + ((size_t)(b*NHEADS+h))*LEN + c*CHUNK;
  size_t rowbase = (size_t)(b*NC + c)*CHUNK;
  float alast = ac[CHUNK-1];
  wv[tid] = dtc[tid] * __expf(alast - ac[tid]);
  int p = tid >> 1, nh = tid & 1;
  float acc[32];
  #pragma unroll
  for (int j=0;j<32;j++) acc[j]=0.f;
  for (int qt=0; qt<4; qt++){
    #pragma unroll
    for (int i=0;i<32;i++){            // x tile 64 x 128
      int e = tid + i*256;
      int pp = e & 127, kk = e >> 7;
      xs[kk][pp] = toF(xbc[(rowbase + qt*64 + kk)*CONV_DIM + (size_t)h*HEADDIM + pp]);
    }
    #pragma unroll
    for (int i=0;i<16;i++){            // B tile 64 x 64
      int e = tid + i*256;
      int n = e & 63, kk = e >> 6;
      Bs[kk][n] = toF(xbc[(rowbase + qt*64 + kk)*CONV_DIM + D_INNER + n]);
    }
    __syncthreads();
    for (int qq=0; qq<64; qq++){
      float wx = wv[qt*64+qq] * xs[qq][p];
      #pragma unroll
      for (int j=0;j<32;j++)
        acc[j] += wx * Bs[qq][nh*32+j];
    }
    __syncthreads();
  }
  float* so = states + (size_t)bid*HEADDIM*D_STATE + (size_t)p*D_STATE + nh*32;
  #pragma unroll
  for (int j=0;j<32;j++) so[j] = acc[j];
}

// ---------------------------------------------------------------------------
// Inter-chunk scan IN PLACE: s = states[idx]; states[idx] = carry;
// carry = carry*cd + s.   grid 32 (b,h), 256 threads, 32 elems per thread.
// ---------------------------------------------------------------------------
__global__ __launch_bounds__(256) void k_scan(
    float* __restrict__ states, const float* __restrict__ cd_t){
  int b = blockIdx.x >> 4, h = blockIdx.x & 15;
  int tid = threadIdx.x;
  float carry[32];
  #pragma unroll
  for (int i=0;i<32;i++) carry[i]=0.f;
  for (int c=0;c<NC;c++){
    size_t base = ((size_t)(b*256 + c*16 + h))*HEADDIM*D_STATE;
    float cd = cd_t[(b*NHEADS+h)*NC + c];
    #pragma unroll
    for (int i=0;i<32;i++){
      size_t idx = base + (size_t)i*256 + tid;
      float s = states[idx];
      states[idx] = carry[i];
      carry[i] = carry[i]*cd + s;
    }
  }
}

// ---------------------------------------------------------------------------
// y = y * silu(z); y = y * rsqrt(mean(y^2)+eps) * norm_w   (in place)
// grid 8192 rows, 256 threads
// ---------------------------------------------------------------------------
__global__ __launch_bounds__(256) void k_gatenorm(
    const bf16* __restrict__ zxbct, const float* __restrict__ norm_w,
    float* __restrict__ y){
  int m = blockIdx.x;
  const bf16* zrow = zxbct + (size_t)m*D_IN_PROJ;
  float* yrow = y + (size_t)m*D_INNER;
  float v[8]; float ss = 0.f;
  #pragma unroll
  for (int i=0;i<8;i++){
    int e = threadIdx.x + i*256;
    float z = toF(zrow[e]);
    float val = yrow[e] * fsilu(z);
    v[i] = val; ss += val*val;
  }
  #pragma unroll
  for (int off=32; off>0; off>>=1) ss += __shfl_down(ss, off, 64);
  __shared__ float red[4];
  if ((threadIdx.x & 63) == 0) red[threadIdx.x >> 6] = ss;
  __syncthreads();
  float tot = red[0]+red[1]+red[2]+red[3];
  float r = rsqrtf(tot * (1.f/D_INNER) + 1e-5f);
  #pragma unroll
  for (int i=0;i<8;i++){
    int e = threadIdx.x + i*256;
    yrow[e] = v[i] * r * norm_w[e];
  }
}

extern "C" void kernel_launch(void* const* d_in, const int* in_sizes, int n_in,
                              void* d_out, int out_size, void* d_ws, size_t ws_size,
                              hipStream_t stream) {
  const float* u         = (const float*)d_in[0];
  const float* in_proj_w = (const float*)d_in[1];
  const float* conv_w    = (const float*)d_in[2];
  const float* conv_b    = (const float*)d_in[3];
  const float* dt_bias   = (const float*)d_in[4];
  const float* A_log     = (const float*)d_in[5];
  const float* Dp        = (const float*)d_in[6];
  const float* norm_w    = (const float*)d_in[7];
  const float* out_proj_w= (const float*)d_in[8];
  float* out = (float*)d_out;

  char* p = (char*)d_ws;
  auto alloc = [&](size_t bytes){ char* r = p; p += (bytes + 255) & ~size_t(255); return r; };
  bf16*  zxbct = (bf16*) alloc((size_t)MROWS*D_IN_PROJ*2);               //  69.5 MB
  bf16*  xbc   = (bf16*) alloc((size_t)MROWS*CONV_DIM*2);                //  35.7 MB
  float* S     = (float*)alloc((size_t)NB*NC*CHUNK*CHUNK*4);             //   8.4 MB
  float* dt_t  = (float*)alloc((size_t)NB*NHEADS*LEN*4);                 //   0.5 MB
  float* acum_t= (float*)alloc((size_t)NB*NHEADS*LEN*4);                 //   0.5 MB
  float* cd_t  = (float*)alloc((size_t)NB*NHEADS*NC*4);                  //   tiny
  float* states= (float*)alloc((size_t)NB*NC*NHEADS*HEADDIM*D_STATE*4);  //  16.8 MB
  float* y     = (float*)alloc((size_t)MROWS*D_INNER*4);                 //  67.1 MB
  // total ~198.5 MB

  dim3 blk(256);
  k_gemm_inproj <<<dim3(MROWS/64, (D_IN_PROJ+63)/64), blk, 0, stream>>>(u, in_proj_w, zxbct);
  k_dt          <<<dim3(NB*NC*NHEADS), blk, 0, stream>>>(zxbct, dt_bias, A_log, dt_t, acum_t, cd_t);
  k_conv        <<<dim3((MROWS*CONV_DIM)/256), blk, 0, stream>>>(zxbct, conv_w, conv_b, xbc);
  k_gemm_scores <<<dim3(4,4,NB*NC), blk, 0, stream>>>(xbc, S);
  k_ydiag       <<<dim3(2, NB*NC*NHEADS), blk, 0, stream>>>(xbc, S, acum_t, dt_t, Dp, y);
  k_states      <<<dim3(NB*NC*NHEADS), blk, 0, stream>>>(xbc, acum_t, dt_t, states);
  k_scan        <<<dim3(NB*NHEADS), blk, 0, stream>>>(states, cd_t);
  k_gemm_yoff   <<<dim3(4,2,NB*NC*NHEADS), blk, 0, stream>>>(xbc, states, acum_t, y);
  k_gatenorm    <<<dim3(MROWS), blk, 0, stream>>>(zxbct, norm_w, y);
  k_gemm_outproj<<<dim3(MROWS/64, D_MODEL/64), blk, 0, stream>>>(y, out_proj_w, out);
}

// Round 3
// 833.586 us; speedup vs baseline: 2.8944x; 2.8944x over previous
//
#include <hip/hip_runtime.h>
#include <hip/hip_bf16.h>
#include <cstdint>
#include <cstddef>

#define D_MODEL   1024
#define D_INNER   2048
#define D_STATE   64
#define HEADDIM   128
#define NHEADS    16
#define D_CONV    4
#define CHUNK     256
#define D_IN_PROJ 4240     // 2*D_INNER + 2*D_STATE + NHEADS
#define ZPAD      4352     // D_IN_PROJ padded to 34*128 for MFMA tiles
#define CONV_DIM  2176     // D_INNER + 2*D_STATE
#define NB        2
#define LEN       4096
#define NC        16       // LEN / CHUNK
#define MROWS     (NB*LEN) // 8192

typedef __hip_bfloat16 bf16;
typedef __bf16 bf16x8 __attribute__((ext_vector_type(8)));
typedef float  f32x4  __attribute__((ext_vector_type(4)));

__device__ __forceinline__ float fsilu(float x){ return x / (1.f + __expf(-x)); }
__device__ __forceinline__ float toF(float x){ return x; }
__device__ __forceinline__ float toF(bf16 x){ return __bfloat162float(x); }
__device__ __forceinline__ void storeF(float* p, float v){ *p = v; }
__device__ __forceinline__ void storeF(bf16* p, float v){ *p = __float2bfloat16(v); }

__device__ __forceinline__ void gload_lds16(const void* g, void* l){
  __builtin_amdgcn_global_load_lds(
     (const __attribute__((address_space(1))) unsigned int*)(uintptr_t)g,
     (__attribute__((address_space(3))) unsigned int*)(uintptr_t)l, 16, 0, 0);
}

// ---------------------------------------------------------------------------
// MFMA bf16 GEMM (m97 structure): C[m,n] = sum_k A[m,k]*B[n,k]
// A: M x K (K-major), B: N x K (K-major, i.e. B^T input), C: M x ldc.
// 128x128 tile / block (256 thr = 4 waves, each wave 64x64), BK=32.
// Requires M%128==0, N%128==0, K%32==0 (caller pads).
// ---------------------------------------------------------------------------
template<typename TC>
__global__ __launch_bounds__(256) void k_gemm_mfma(
    const bf16* __restrict__ A, int lda,
    const bf16* __restrict__ B, int ldb,
    TC* __restrict__ C, int ldc, int K)
{
  __shared__ __align__(16) bf16 As[128*32];
  __shared__ __align__(16) bf16 Bs[128*32];
  const int tid = threadIdx.x;
  const int w = tid >> 6, l = tid & 63;
  const int m0 = blockIdx.x*128, n0 = blockIdx.y*128;
  const int wm = (w & 1)*64, wn = (w >> 1)*64;
  f32x4 acc[4][4] = {};

  const int sr = l >> 2;        // staging row within 16-row block
  const int sc = (l & 3)*8;     // staging col (bf16 elems)

  for (int k0 = 0; k0 < K; k0 += 32) {
    #pragma unroll
    for (int j = 0; j < 2; j++) {
      const int blk = w*2 + j;                 // 0..7, wave-uniform
      const int row = blk*16 + sr;
      gload_lds16(A + (size_t)(m0+row)*lda + k0 + sc, (char*)As + blk*1024);
      gload_lds16(B + (size_t)(n0+row)*ldb + k0 + sc, (char*)Bs + blk*1024);
    }
    asm volatile("s_waitcnt vmcnt(0)" ::: "memory");
    __syncthreads();

    const int kq = (l >> 4)*8;
    const int rA = wm + (l & 15);
    const int rB = wn + (l & 15);
    bf16x8 af[4], bfr[4];
    #pragma unroll
    for (int t = 0; t < 4; t++){
      af[t]  = *(const bf16x8*)&As[(rA + t*16)*32 + kq];
      bfr[t] = *(const bf16x8*)&Bs[(rB + t*16)*32 + kq];
    }
    #pragma unroll
    for (int tm = 0; tm < 4; tm++)
      #pragma unroll
      for (int tn = 0; tn < 4; tn++)
        acc[tm][tn] = __builtin_amdgcn_mfma_f32_16x16x32_bf16(af[tm], bfr[tn], acc[tm][tn], 0,0,0);
    __syncthreads();
  }

  // epilogue: C/D layout col=lane&15, row=(lane>>4)*4+reg
  const int col   = n0 + wn + (l & 15);
  const int rbase = m0 + wm + (l >> 4)*4;
  #pragma unroll
  for (int tm = 0; tm < 4; tm++)
    #pragma unroll
    for (int tn = 0; tn < 4; tn++)
      #pragma unroll
      for (int i = 0; i < 4; i++){
        int r = rbase + tm*16 + i;
        storeF(&C[(size_t)r*ldc + (col + tn*16)], acc[tm][tn][i]);
      }
}

// ---------------------------------------------------------------------------
// fp32<->bf16 conversion helpers
// ---------------------------------------------------------------------------
__global__ __launch_bounds__(256) void k_tobf16(
    const float* __restrict__ src, bf16* __restrict__ dst, int n){
  int i = blockIdx.x*256 + threadIdx.x;
  if (i < n) dst[i] = __float2bfloat16(src[i]);
}

// in_proj_w (4240 x 1024) -> bf16 padded to 4352 rows (pad rows = 0)
__global__ __launch_bounds__(256) void k_padW(
    const float* __restrict__ W, bf16* __restrict__ Wb){
  int i = blockIdx.x*256 + threadIdx.x;   // < ZPAD*1024
  int r = i >> 10;
  Wb[i] = __float2bfloat16((r < D_IN_PROJ) ? W[i] : 0.f);
}

// ---------------------------------------------------------------------------
// Generic fp32-accum tiled GEMM (both operands K-major), small shapes:
//   C[m,n] (+)= [exp(rs[m])] * sum_k A[m,k]*B[n,k]
// ---------------------------------------------------------------------------
template<typename TA, typename TB, typename TC, bool ACCUM, bool ROWSCALE_EXP>
__device__ __forceinline__ void gemm_body(
    const TA* __restrict__ A, int lda,
    const TB* __restrict__ B, int ldb,
    TC* __restrict__ C, int ldc,
    int M, int N, int K,
    const float* __restrict__ rs,
    int mt, int nt)
{
  __shared__ float As[16][68];
  __shared__ float Bs[16][68];
  const int tid = threadIdx.x;
  const int tx = tid & 15, ty = tid >> 4;
  const int m0 = mt*64, n0 = nt*64;
  float acc[4][4] = {};
  for (int k0 = 0; k0 < K; k0 += 16) {
    #pragma unroll
    for (int i = 0; i < 4; i++) {
      int e = tid + i*256;
      int k = e & 15, m = e >> 4;
      int gm = m0 + m;
      As[k][m] = (gm < M) ? toF(A[(size_t)gm*lda + (k0+k)]) : 0.f;
      int gn = n0 + m;
      Bs[k][m] = (gn < N) ? toF(B[(size_t)gn*ldb + (k0+k)]) : 0.f;
    }
    __syncthreads();
    #pragma unroll
    for (int kk = 0; kk < 16; kk++) {
      float a[4], b[4];
      #pragma unroll
      for (int i=0;i<4;i++) a[i] = As[kk][ty*4+i];
      #pragma unroll
      for (int j=0;j<4;j++) b[j] = Bs[kk][tx*4+j];
      #pragma unroll
      for (int i=0;i<4;i++)
        #pragma unroll
        for (int j=0;j<4;j++)
          acc[i][j] += a[i]*b[j];
    }
    __syncthreads();
  }
  #pragma unroll
  for (int i=0;i<4;i++){
    int gm = m0 + ty*4 + i;
    if (gm >= M) continue;
    float sc = 1.f;
    if (ROWSCALE_EXP) sc = __expf(rs[gm]);
    #pragma unroll
    for (int j=0;j<4;j++){
      int gn = n0 + tx*4 + j;
      if (gn >= N) continue;
      size_t idx = (size_t)gm*ldc + gn;
      float v = acc[i][j]*sc;
      float old = ACCUM ? toF(C[idx]) : 0.f;
      storeF(&C[idx], v + old);
    }
  }
}

// S[z][q,k] = Cc[q,:] . Bc[k,:]   per chunk z   (256x256, K=64)
__global__ __launch_bounds__(256) void k_gemm_scores(
    const bf16* __restrict__ xbc, float* __restrict__ S){
  int z = blockIdx.z;
  const bf16* Cc = xbc + (size_t)z*CHUNK*CONV_DIM + (D_INNER + D_STATE);
  const bf16* Bc = xbc + (size_t)z*CHUNK*CONV_DIM + D_INNER;
  gemm_body<bf16,bf16,float,false,false>(Cc, CONV_DIM, Bc, CONV_DIM,
                         S + (size_t)z*CHUNK*CHUNK, CHUNK,
                         CHUNK, CHUNK, D_STATE, nullptr, blockIdx.x, blockIdx.y);
}

// y[q, h*128+p] += exp(acum[q]) * sum_n C[q,n]*prev[h][p,n]   (256x128, K=64)
__global__ __launch_bounds__(256) void k_gemm_yoff(
    const bf16* __restrict__ xbc, const float* __restrict__ prev,
    const float* __restrict__ acum_t, bf16* __restrict__ y){
  int bid = blockIdx.z;
  int h = bid & 15, c = (bid>>4) & 15, b = bid >> 8;
  int z = b*NC + c;
  const bf16* Aop = xbc + (size_t)z*CHUNK*CONV_DIM + (D_INNER + D_STATE);
  const float* Bop = prev + (size_t)bid*HEADDIM*D_STATE;
  bf16* Cout = y + (size_t)z*CHUNK*D_INNER + h*HEADDIM;
  const float* rs = acum_t + ((size_t)(b*NHEADS + h))*LEN + c*CHUNK;
  gemm_body<bf16,float,bf16,true,true>(Aop, CONV_DIM, Bop, D_STATE, Cout, D_INNER,
                       CHUNK, HEADDIM, D_STATE, rs, blockIdx.x, blockIdx.y);
}

// ---------------------------------------------------------------------------
// dt = softplus(dt_raw + dt_bias); a = dt*A; inclusive cumsum over chunk.
// ---------------------------------------------------------------------------
__global__ __launch_bounds__(256) void k_dt(
    const bf16* __restrict__ zxbct, const float* __restrict__ dt_bias,
    const float* __restrict__ A_log, float* __restrict__ dt_t,
    float* __restrict__ acum_t, float* __restrict__ cd_t){
  int bid = blockIdx.x;
  int h = bid & 15, c = (bid>>4)&15, b = bid>>8;
  int q = threadIdx.x;
  size_t m = (size_t)(b*NC + c)*CHUNK + q;
  float x = toF(zxbct[m*ZPAD + (D_INNER + CONV_DIM) + h]) + dt_bias[h];
  float dtv = (x > 20.f) ? x : log1pf(__expf(x));
  float Ah = -__expf(A_log[h]);
  float a = dtv * Ah;
  __shared__ float sb[CHUNK];
  sb[q] = a;
  __syncthreads();
  #pragma unroll
  for (int off=1; off<CHUNK; off<<=1){
    float t = (q >= off) ? sb[q-off] : 0.f;
    __syncthreads();
    sb[q] += t;
    __syncthreads();
  }
  float ac = sb[q];
  size_t o = ((size_t)(b*NHEADS+h))*LEN + c*CHUNK + q;
  dt_t[o]   = dtv;
  acum_t[o] = ac;
  if (q == CHUNK-1) cd_t[(b*NHEADS+h)*NC + c] = __expf(ac);
}

// ---------------------------------------------------------------------------
// Depthwise causal conv (4 taps) + SiLU.
// ---------------------------------------------------------------------------
__global__ __launch_bounds__(256) void k_conv(
    const bf16* __restrict__ zxbct, const float* __restrict__ conv_w,
    const float* __restrict__ conv_b, bf16* __restrict__ xbc){
  int idx = blockIdx.x*256 + threadIdx.x;
  int ch = idx % CONV_DIM;
  int m  = idx / CONV_DIM;
  int l  = m & (LEN-1);
  float acc = conv_b[ch];
  #pragma unroll
  for (int w=0; w<D_CONV; w++){
    int lw = l - (D_CONV-1) + w;
    if (lw >= 0)
      acc += toF(zxbct[((size_t)(m - (D_CONV-1) + w))*ZPAD + D_INNER + ch]) * conv_w[ch*D_CONV + w];
  }
  storeF(&xbc[(size_t)idx], fsilu(acc));
}

// ---------------------------------------------------------------------------
// y_diag[q,p] = sum_{k<=q} S[q,k]*exp(acum[q]-acum[k])*dt[k]*x[k,p]  (+ x*Dp)
// ---------------------------------------------------------------------------
__global__ __launch_bounds__(256) void k_ydiag(
    const bf16* __restrict__ xbc, const float* __restrict__ S,
    const float* __restrict__ acum_t, const float* __restrict__ dt_t,
    const float* __restrict__ Dp, bf16* __restrict__ y){
  int qt = blockIdx.x;
  int bid = blockIdx.y;
  int h = bid & 15, c = (bid>>4)&15, b = bid>>8;
  const int q0 = qt*128;
  int tid = threadIdx.x; int tx = tid & 15, ty = tid >> 4;
  __shared__ float xs[32][132];
  __shared__ float Ss[32][132];
  __shared__ float aks[32], dks[32];
  const float* acum = acum_t + ((size_t)(b*NHEADS+h))*LEN + c*CHUNK;
  const float* dtc  = dt_t   + ((size_t)(b*NHEADS+h))*LEN + c*CHUNK;
  const float* Sbc  = S + ((size_t)(b*NC+c))*CHUNK*CHUNK;
  size_t xrowbase = ((size_t)(b*NC + c))*CHUNK*CONV_DIM + (size_t)h*HEADDIM;
  float accq[8];
  #pragma unroll
  for (int i=0;i<8;i++){ accq[i] = acum[q0 + ty*8 + i]; }
  float acc[8][8] = {};
  const int kmax = q0 + 128;
  for (int k0 = 0; k0 < kmax; k0 += 32) {
    #pragma unroll
    for (int i=0;i<16;i++){
      int e = tid + i*256;
      int p = e & 127, kk = e >> 7;
      xs[kk][p] = toF(xbc[xrowbase + (size_t)(k0+kk)*CONV_DIM + p]);
    }
    #pragma unroll
    for (int i=0;i<16;i++){
      int e = tid + i*256;
      int kk = e & 31, qq = e >> 5;
      Ss[kk][qq] = Sbc[(size_t)(q0+qq)*CHUNK + k0 + kk];
    }
    if (tid < 32) { aks[tid] = acum[k0+tid]; dks[tid] = dtc[k0+tid]; }
    __syncthreads();
    for (int kk=0; kk<32; kk++) {
      int k = k0 + kk;
      float ak = aks[kk], dk = dks[kk];
      float coef[8];
      #pragma unroll
      for (int i=0;i<8;i++){
        int q = q0 + ty*8 + i;
        float cf = Ss[kk][ty*8+i] * __expf(accq[i]-ak) * dk;
        coef[i] = (k <= q) ? cf : 0.f;
      }
      #pragma unroll
      for (int j=0;j<8;j++){
        float xv = xs[kk][tx*8+j];
        #pragma unroll
        for (int i=0;i<8;i++) acc[i][j] += coef[i]*xv;
      }
    }
    __syncthreads();
  }
  float dph = Dp[h];
  size_t yrow = ((size_t)(b*NC + c))*CHUNK*D_INNER + (size_t)h*HEADDIM;
  #pragma unroll
  for (int i=0;i<8;i++){
    int q = q0 + ty*8 + i;
    #pragma unroll
    for (int j=0;j<8;j++){
      int p = tx*8 + j;
      float xv = toF(xbc[xrowbase + (size_t)q*CONV_DIM + p]);
      storeF(&y[yrow + (size_t)q*D_INNER + p], acc[i][j] + xv*dph);
    }
  }
}

// ---------------------------------------------------------------------------
// states[b,c,h][p,n] = sum_q dt[q]*exp(acum[255]-acum[q]) * x[q,p] * B[q,n]
// ---------------------------------------------------------------------------
__global__ __launch_bounds__(256) void k_states(
    const bf16* __restrict__ xbc, const float* __restrict__ acum_t,
    const float* __restrict__ dt_t, float* __restrict__ states){
  int bid = blockIdx.x;
  int h = bid & 15, c = (bid>>4)&15, b = bid>>8;
  int tid = threadIdx.x;
  __shared__ float wv[CHUNK];
  __shared__ float Bs[64][65];
  __shared__ float xs[64][128];
  const float* ac  = acum_t + ((size_t)(b*NHEADS+h))*LEN + c*CHUNK;
  const float* dtc = dt_t   + ((size_t)(b*NHEADS+h))*LEN + c*CHUNK;
  size_t rowbase = (size_t)(b*NC + c)*CHUNK;
  float alast = ac[CHUNK-1];
  wv[tid] = dtc[tid] * __expf(alast - ac[tid]);
  int p = tid >> 1, nh = tid & 1;
  float acc[32];
  #pragma unroll
  for (int j=0;j<32;j++) acc[j]=0.f;
  for (int qt=0; qt<4; qt++){
    #pragma unroll
    for (int i=0;i<32;i++){
      int e = tid + i*256;
      int pp = e & 127, kk = e >> 7;
      xs[kk][pp] = toF(xbc[(rowbase + qt*64 + kk)*CONV_DIM + (size_t)h*HEADDIM + pp]);
    }
    #pragma unroll
    for (int i=0;i<16;i++){
      int e = tid + i*256;
      int n = e & 63, kk = e >> 6;
      Bs[kk][n] = toF(xbc[(rowbase + qt*64 + kk)*CONV_DIM + D_INNER + n]);
    }
    __syncthreads();
    for (int qq=0; qq<64; qq++){
      float wx = wv[qt*64+qq] * xs[qq][p];
      #pragma unroll
      for (int j=0;j<32;j++)
        acc[j] += wx * Bs[qq][nh*32+j];
    }
    __syncthreads();
  }
  float* so = states + (size_t)bid*HEADDIM*D_STATE + (size_t)p*D_STATE + nh*32;
  #pragma unroll
  for (int j=0;j<32;j++) so[j] = acc[j];
}

// ---------------------------------------------------------------------------
// Inter-chunk scan IN PLACE.
// ---------------------------------------------------------------------------
__global__ __launch_bounds__(256) void k_scan(
    float* __restrict__ states, const float* __restrict__ cd_t){
  int b = blockIdx.x >> 4, h = blockIdx.x & 15;
  int tid = threadIdx.x;
  float carry[32];
  #pragma unroll
  for (int i=0;i<32;i++) carry[i]=0.f;
  for (int c=0;c<NC;c++){
    size_t base = ((size_t)(b*256 + c*16 + h))*HEADDIM*D_STATE;
    float cd = cd_t[(b*NHEADS+h)*NC + c];
    #pragma unroll
    for (int i=0;i<32;i++){
      size_t idx = base + (size_t)i*256 + tid;
      float s = states[idx];
      states[idx] = carry[i];
      carry[i] = carry[i]*cd + s;
    }
  }
}

// ---------------------------------------------------------------------------
// y = y * silu(z); y = y * rsqrt(mean(y^2)+eps) * norm_w   (in place, bf16)
// ---------------------------------------------------------------------------
__global__ __launch_bounds__(256) void k_gatenorm(
    const bf16* __restrict__ zxbct, const float* __restrict__ norm_w,
    bf16* __restrict__ y){
  int m = blockIdx.x;
  const bf16* zrow = zxbct + (size_t)m*ZPAD;
  bf16* yrow = y + (size_t)m*D_INNER;
  float v[8]; float ss = 0.f;
  #pragma unroll
  for (int i=0;i<8;i++){
    int e = threadIdx.x + i*256;
    float z = toF(zrow[e]);
    float val = toF(yrow[e]) * fsilu(z);
    v[i] = val; ss += val*val;
  }
  #pragma unroll
  for (int off=32; off>0; off>>=1) ss += __shfl_down(ss, off, 64);
  __shared__ float red[4];
  if ((threadIdx.x & 63) == 0) red[threadIdx.x >> 6] = ss;
  __syncthreads();
  float tot = red[0]+red[1]+red[2]+red[3];
  float r = rsqrtf(tot * (1.f/D_INNER) + 1e-5f);
  #pragma unroll
  for (int i=0;i<8;i++){
    int e = threadIdx.x + i*256;
    storeF(&yrow[e], v[i] * r * norm_w[e]);
  }
}

extern "C" void kernel_launch(void* const* d_in, const int* in_sizes, int n_in,
                              void* d_out, int out_size, void* d_ws, size_t ws_size,
                              hipStream_t stream) {
  const float* u         = (const float*)d_in[0];
  const float* in_proj_w = (const float*)d_in[1];
  const float* conv_w    = (const float*)d_in[2];
  const float* conv_b    = (const float*)d_in[3];
  const float* dt_bias   = (const float*)d_in[4];
  const float* A_log     = (const float*)d_in[5];
  const float* Dp        = (const float*)d_in[6];
  const float* norm_w    = (const float*)d_in[7];
  const float* out_proj_w= (const float*)d_in[8];
  float* out = (float*)d_out;

  char* p = (char*)d_ws;
  auto alloc = [&](size_t bytes){ char* r = p; p += (bytes + 255) & ~size_t(255); return r; };
  bf16*  zxbct = (bf16*) alloc((size_t)MROWS*ZPAD*2);                    //  71.3 MB
  bf16*  xbc   = (bf16*) alloc((size_t)MROWS*CONV_DIM*2);                //  35.7 MB
  bf16*  y     = (bf16*) alloc((size_t)MROWS*D_INNER*2);                 //  33.6 MB
  bf16*  ub    = (bf16*) alloc((size_t)MROWS*D_MODEL*2);                 //  16.8 MB (aliased by states)
  bf16*  Wb_in = (bf16*) alloc((size_t)ZPAD*D_MODEL*2);                  //   8.9 MB (aliased by S)
  bf16*  Wb_out= (bf16*) alloc((size_t)D_MODEL*D_INNER*2);               //   4.2 MB
  float* dt_t  = (float*)alloc((size_t)NB*NHEADS*LEN*4);                 //   0.5 MB
  float* acum_t= (float*)alloc((size_t)NB*NHEADS*LEN*4);                 //   0.5 MB
  float* cd_t  = (float*)alloc((size_t)NB*NHEADS*NC*4);                  //   tiny
  // aliases (lifetimes do not overlap with their hosts):
  float* states= (float*)ub;    // 16.8 MB, used after in_proj GEMM done
  float* S     = (float*)Wb_in; //  8.4 MB, used after in_proj GEMM done
  // total ~171.5 MB

  dim3 blk(256);
  // convert inputs to bf16
  k_tobf16<<<dim3((MROWS*D_MODEL+255)/256), blk, 0, stream>>>(u, ub, MROWS*D_MODEL);
  k_padW  <<<dim3((ZPAD*D_MODEL)/256), blk, 0, stream>>>(in_proj_w, Wb_in);
  k_tobf16<<<dim3((D_MODEL*D_INNER+255)/256), blk, 0, stream>>>(out_proj_w, Wb_out, D_MODEL*D_INNER);

  // zxbct = u @ in_proj_w^T  (8192 x 4352, K=1024)  [MFMA]
  k_gemm_mfma<bf16><<<dim3(MROWS/128, ZPAD/128), blk, 0, stream>>>(
      ub, D_MODEL, Wb_in, D_MODEL, zxbct, ZPAD, D_MODEL);

  k_dt          <<<dim3(NB*NC*NHEADS), blk, 0, stream>>>(zxbct, dt_bias, A_log, dt_t, acum_t, cd_t);
  k_conv        <<<dim3((MROWS*CONV_DIM)/256), blk, 0, stream>>>(zxbct, conv_w, conv_b, xbc);
  k_gemm_scores <<<dim3(4,4,NB*NC), blk, 0, stream>>>(xbc, S);
  k_ydiag       <<<dim3(2, NB*NC*NHEADS), blk, 0, stream>>>(xbc, S, acum_t, dt_t, Dp, y);
  k_states      <<<dim3(NB*NC*NHEADS), blk, 0, stream>>>(xbc, acum_t, dt_t, states);
  k_scan        <<<dim3(NB*NHEADS), blk, 0, stream>>>(states, cd_t);
  k_gemm_yoff   <<<dim3(4,2,NB*NC*NHEADS), blk, 0, stream>>>(xbc, states, acum_t, y);
  k_gatenorm    <<<dim3(MROWS), blk, 0, stream>>>(zxbct, norm_w, y);

  // out = y @ out_proj_w^T  (8192 x 1024, K=2048)  [MFMA]
  k_gemm_mfma<float><<<dim3(MROWS/128, D_MODEL/128), blk, 0, stream>>>(
      y, D_INNER, Wb_out, D_INNER, out, D_MODEL, D_INNER);
}

// Round 4
// 531.056 us; speedup vs baseline: 4.5432x; 1.5697x over previous
//
#include <hip/hip_runtime.h>
#include <hip/hip_bf16.h>
#include <cstdint>
#include <cstddef>

#define D_MODEL   1024
#define D_INNER   2048
#define D_STATE   64
#define HEADDIM   128
#define NHEADS    16
#define D_CONV    4
#define CHUNK     256
#define D_IN_PROJ 4240     // 2*D_INNER + 2*D_STATE + NHEADS
#define ZPAD      4352     // padded for MFMA tiles
#define CONV_DIM  2176     // D_INNER + 2*D_STATE
#define NB        2
#define LEN       4096
#define NC        16
#define MROWS     (NB*LEN) // 8192

typedef __hip_bfloat16 bf16;
typedef __bf16 bf16x8 __attribute__((ext_vector_type(8)));
typedef float  f32x4  __attribute__((ext_vector_type(4)));

__device__ __forceinline__ float fsilu(float x){ return x / (1.f + __expf(-x)); }
__device__ __forceinline__ float toF(float x){ return x; }
__device__ __forceinline__ float toF(bf16 x){ return __bfloat162float(x); }
__device__ __forceinline__ void storeF(float* p, float v){ *p = v; }
__device__ __forceinline__ void storeF(bf16* p, float v){ *p = __float2bfloat16(v); }

__device__ __forceinline__ void gload_lds16(const void* g, void* l){
  __builtin_amdgcn_global_load_lds(
     (const __attribute__((address_space(1))) unsigned int*)(uintptr_t)g,
     (__attribute__((address_space(3))) unsigned int*)(uintptr_t)l, 16, 0, 0);
}

// ---------------------------------------------------------------------------
// MFMA bf16 GEMM (m97 structure): C[m,n] = sum_k A[m,k]*B[n,k]
// ---------------------------------------------------------------------------
template<typename TC>
__global__ __launch_bounds__(256) void k_gemm_mfma(
    const bf16* __restrict__ A, int lda,
    const bf16* __restrict__ B, int ldb,
    TC* __restrict__ C, int ldc, int K)
{
  __shared__ __align__(16) bf16 As[128*32];
  __shared__ __align__(16) bf16 Bs[128*32];
  const int tid = threadIdx.x;
  const int w = tid >> 6, l = tid & 63;
  const int m0 = blockIdx.x*128, n0 = blockIdx.y*128;
  const int wm = (w & 1)*64, wn = (w >> 1)*64;
  f32x4 acc[4][4] = {};
  const int sr = l >> 2;
  const int sc = (l & 3)*8;

  for (int k0 = 0; k0 < K; k0 += 32) {
    #pragma unroll
    for (int j = 0; j < 2; j++) {
      const int blk = w*2 + j;
      const int row = blk*16 + sr;
      gload_lds16(A + (size_t)(m0+row)*lda + k0 + sc, (char*)As + blk*1024);
      gload_lds16(B + (size_t)(n0+row)*ldb + k0 + sc, (char*)Bs + blk*1024);
    }
    asm volatile("s_waitcnt vmcnt(0)" ::: "memory");
    __syncthreads();

    const int kq = (l >> 4)*8;
    const int rA = wm + (l & 15);
    const int rB = wn + (l & 15);
    bf16x8 af[4], bfr[4];
    #pragma unroll
    for (int t = 0; t < 4; t++){
      af[t]  = *(const bf16x8*)&As[(rA + t*16)*32 + kq];
      bfr[t] = *(const bf16x8*)&Bs[(rB + t*16)*32 + kq];
    }
    #pragma unroll
    for (int tm = 0; tm < 4; tm++)
      #pragma unroll
      for (int tn = 0; tn < 4; tn++)
        acc[tm][tn] = __builtin_amdgcn_mfma_f32_16x16x32_bf16(af[tm], bfr[tn], acc[tm][tn], 0,0,0);
    __syncthreads();
  }

  const int col   = n0 + wn + (l & 15);
  const int rbase = m0 + wm + (l >> 4)*4;
  #pragma unroll
  for (int tm = 0; tm < 4; tm++)
    #pragma unroll
    for (int tn = 0; tn < 4; tn++)
      #pragma unroll
      for (int i = 0; i < 4; i++){
        int r = rbase + tm*16 + i;
        storeF(&C[(size_t)r*ldc + (col + tn*16)], acc[tm][tn][i]);
      }
}

// ---------------------------------------------------------------------------
// conversions
// ---------------------------------------------------------------------------
__global__ __launch_bounds__(256) void k_tobf16(
    const float* __restrict__ src, bf16* __restrict__ dst, int n){
  int i = blockIdx.x*256 + threadIdx.x;
  if (i < n) dst[i] = __float2bfloat16(src[i]);
}

__global__ __launch_bounds__(256) void k_padW(
    const float* __restrict__ W, bf16* __restrict__ Wb){
  int i = blockIdx.x*256 + threadIdx.x;
  int r = i >> 10;
  Wb[i] = __float2bfloat16((r < D_IN_PROJ) ? W[i] : 0.f);
}

// ---------------------------------------------------------------------------
// dt = softplus(dt_raw + dt_bias); a = dt*A; inclusive cumsum over chunk.
// ---------------------------------------------------------------------------
__global__ __launch_bounds__(256) void k_dt(
    const bf16* __restrict__ zxbct, const float* __restrict__ dt_bias,
    const float* __restrict__ A_log, float* __restrict__ dt_t,
    float* __restrict__ acum_t, float* __restrict__ cd_t){
  int bid = blockIdx.x;
  int h = bid & 15, c = (bid>>4)&15, b = bid>>8;
  int q = threadIdx.x;
  size_t m = (size_t)(b*NC + c)*CHUNK + q;
  float x = toF(zxbct[m*ZPAD + (D_INNER + CONV_DIM) + h]) + dt_bias[h];
  float dtv = (x > 20.f) ? x : log1pf(__expf(x));
  float Ah = -__expf(A_log[h]);
  float a = dtv * Ah;
  __shared__ float sb[CHUNK];
  sb[q] = a;
  __syncthreads();
  #pragma unroll
  for (int off=1; off<CHUNK; off<<=1){
    float t = (q >= off) ? sb[q-off] : 0.f;
    __syncthreads();
    sb[q] += t;
    __syncthreads();
  }
  float ac = sb[q];
  size_t o = ((size_t)(b*NHEADS+h))*LEN + c*CHUNK + q;
  dt_t[o]   = dtv;
  acum_t[o] = ac;
  if (q == CHUNK-1) cd_t[(b*NHEADS+h)*NC + c] = __expf(ac);
}

// ---------------------------------------------------------------------------
// Depthwise causal conv (4 taps) + SiLU.  One thread per (m, 8 channels).
// ---------------------------------------------------------------------------
__global__ __launch_bounds__(256) void k_conv(
    const bf16* __restrict__ zxbct, const float* __restrict__ conv_w,
    const float* __restrict__ conv_b, bf16* __restrict__ xbc){
  int idx = blockIdx.x*256 + threadIdx.x;   // MROWS * 272
  int cg = idx % (CONV_DIM/8);
  int m  = idx / (CONV_DIM/8);
  int ch = cg*8;
  int l  = m & (LEN-1);
  float acc[8];
  #pragma unroll
  for (int j=0;j<8;j++) acc[j] = conv_b[ch+j];
  #pragma unroll
  for (int w=0; w<D_CONV; w++){
    if (l - (D_CONV-1) + w >= 0){
      bf16x8 v = *(const bf16x8*)(zxbct + (size_t)(m - (D_CONV-1) + w)*ZPAD + D_INNER + ch);
      #pragma unroll
      for (int j=0;j<8;j++) acc[j] += (float)v[j] * conv_w[(ch+j)*D_CONV + w];
    }
  }
  bf16x8 o;
  #pragma unroll
  for (int j=0;j<8;j++) o[j] = (__bf16)fsilu(acc[j]);
  *(bf16x8*)(xbc + (size_t)m*CONV_DIM + ch) = o;
}

// ---------------------------------------------------------------------------
// FUSED per (b,c,h): scores (MFMA) -> coef+mask+Dp -> y_diag (MFMA),
// plus chunk states (MFMA).  4 waves, wave w owns q in [w*64, w*64+64).
// LDS: xsT (x^T tile), bts (w-scaled B^T tile), Ms (per-wave M tile), acs.
// ---------------------------------------------------------------------------
__global__ __launch_bounds__(256,2) void k_fused(
    const bf16* __restrict__ xbc, const float* __restrict__ acum_t,
    const float* __restrict__ dt_t, const float* __restrict__ Dp,
    bf16* __restrict__ y, float* __restrict__ states)
{
  const int bid = blockIdx.x;
  const int h = bid & 15, c = (bid>>4)&15, b = bid>>8;
  const int z = b*NC + c;
  const int tid = threadIdx.x;
  const int w = tid >> 6, l = tid & 63;
  const int quad = l >> 4, lq = l & 15;

  __shared__ __align__(16) __bf16 xsT[128*72];   // xsT[p][k], pad 72
  __shared__ __align__(16) __bf16 bts[64*72];    // bts[n][k] = B[k][n]*w[k]
  __shared__ __align__(16) __bf16 Ms[4][64*72];  // per-wave M tile [q][k]
  __shared__ float acs[CHUNK];

  const float* acum = acum_t + ((size_t)(b*NHEADS+h))*LEN + c*CHUNK;
  const float* dtc  = dt_t   + ((size_t)(b*NHEADS+h))*LEN + c*CHUNK;
  const float alast = acum[CHUNK-1];
  acs[tid] = acum[tid];

  const bf16* xrow = xbc + (size_t)z*CHUNK*CONV_DIM + h*HEADDIM;
  const bf16* Brow = xbc + (size_t)z*CHUNK*CONV_DIM + D_INNER;
  const bf16* Crow = xbc + (size_t)z*CHUNK*CONV_DIM + D_INNER + D_STATE;
  const float Dph = Dp[h];
  const int qw = w*64;

  f32x4 Yacc[4][8] = {};    // [qm][pn]
  f32x4 Sst[2][4]  = {};    // states: [mi (p 32/wave)][ni]

  for (int t = 0; t < 4; t++){
    const int k0 = t*64;
    __syncthreads();
    // ---- stage xsT (transposed): lane l -> time k0+l
    {
      const bf16* xr = xrow + (size_t)(k0+l)*CONV_DIM;
      #pragma unroll
      for (int pass=0; pass<4; pass++){
        int pb = w*8 + pass*32;
        bf16x8 v = *(const bf16x8*)(xr + pb);
        #pragma unroll
        for (int j=0;j<8;j++) xsT[(pb+j)*72 + l] = v[j];
      }
      // ---- stage bts (transposed, scaled by w[k] = dt[k]*exp(alast-acum[k]))
      float wl = dtc[k0+l] * __expf(alast - acum[k0+l]);
      const bf16* br = Brow + (size_t)(k0+l)*CONV_DIM;
      #pragma unroll
      for (int pass=0; pass<2; pass++){
        int nb = w*8 + pass*32;
        bf16x8 v = *(const bf16x8*)(br + nb);
        #pragma unroll
        for (int j=0;j<8;j++) bts[(nb+j)*72 + l] = (__bf16)((float)v[j] * wl);
      }
    }
    __syncthreads();

    // ---- states: wave w handles p in [w*32, w*32+32)
    #pragma unroll
    for (int s=0;s<2;s++){
      bf16x8 bf_[4];
      #pragma unroll
      for (int ni=0;ni<4;ni++)
        bf_[ni] = *(const bf16x8*)&bts[(ni*16+lq)*72 + s*32 + quad*8];
      #pragma unroll
      for (int mi=0;mi<2;mi++){
        bf16x8 a = *(const bf16x8*)&xsT[(w*32 + mi*16 + lq)*72 + s*32 + quad*8];
        #pragma unroll
        for (int ni=0;ni<4;ni++)
          Sst[mi][ni] = __builtin_amdgcn_mfma_f32_16x16x32_bf16(a, bf_[ni], Sst[mi][ni], 0,0,0);
      }
    }

    // ---- y_diag: wave w participates for tiles t <= w
    if (t <= w){
      float dk4[4], ak4[4];
      #pragma unroll
      for (int kn=0;kn<4;kn++){
        int kl = k0 + kn*16 + lq;
        dk4[kn] = dtc[kl];
        ak4[kn] = acs[kl];
      }
      #pragma unroll
      for (int qm=0;qm<4;qm++){
        f32x4 Sacc[4] = {};
        #pragma unroll
        for (int s=0;s<2;s++){
          bf16x8 af = *(const bf16x8*)(Crow + (size_t)(qw+qm*16+lq)*CONV_DIM + s*32 + quad*8);
          #pragma unroll
          for (int kn=0;kn<4;kn++){
            bf16x8 bf_ = *(const bf16x8*)(Brow + (size_t)(k0+kn*16+lq)*CONV_DIM + s*32 + quad*8);
            Sacc[kn] = __builtin_amdgcn_mfma_f32_16x16x32_bf16(af, bf_, Sacc[kn], 0,0,0);
          }
        }
        float aq4[4];
        #pragma unroll
        for (int i=0;i<4;i++) aq4[i] = acs[qw+qm*16+quad*4+i];
        #pragma unroll
        for (int kn=0;kn<4;kn++)
          #pragma unroll
          for (int i=0;i<4;i++){
            int ql = qw + qm*16 + quad*4 + i;
            int kl = k0 + kn*16 + lq;
            float v = Sacc[kn][i] * __expf(aq4[i]-ak4[kn]) * dk4[kn];
            v = (kl < ql) ? v : ((kl == ql) ? v + Dph : 0.f);
            Ms[w][(qm*16+quad*4+i)*72 + kn*16+lq] = (__bf16)v;
          }
      }
      asm volatile("s_waitcnt lgkmcnt(0)" ::: "memory");
      #pragma unroll
      for (int s2=0;s2<2;s2++){
        bf16x8 bp[8];
        #pragma unroll
        for (int pn=0;pn<8;pn++)
          bp[pn] = *(const bf16x8*)&xsT[(pn*16+lq)*72 + s2*32 + quad*8];
        #pragma unroll
        for (int qm=0;qm<4;qm++){
          bf16x8 am = *(const bf16x8*)&Ms[w][(qm*16+lq)*72 + s2*32 + quad*8];
          #pragma unroll
          for (int pn=0;pn<8;pn++)
            Yacc[qm][pn] = __builtin_amdgcn_mfma_f32_16x16x32_bf16(am, bp[pn], Yacc[qm][pn], 0,0,0);
        }
      }
    }
  }

  // ---- epilogue: y (bf16)
  bf16* yrow = y + (size_t)z*CHUNK*D_INNER + h*HEADDIM;
  #pragma unroll
  for (int qm=0;qm<4;qm++)
    #pragma unroll
    for (int pn=0;pn<8;pn++)
      #pragma unroll
      for (int i=0;i<4;i++){
        int q = qw + qm*16 + quad*4 + i;
        int p = pn*16 + lq;
        storeF(&yrow[(size_t)q*D_INNER + p], Yacc[qm][pn][i]);
      }
  // ---- epilogue: states (fp32)
  float* so = states + (size_t)bid*HEADDIM*D_STATE;
  #pragma unroll
  for (int mi=0;mi<2;mi++)
    #pragma unroll
    for (int ni=0;ni<4;ni++)
      #pragma unroll
      for (int i=0;i<4;i++){
        int pp = w*32 + mi*16 + quad*4 + i;
        int n = ni*16 + lq;
        so[pp*D_STATE + n] = Sst[mi][ni][i];
      }
}

// ---------------------------------------------------------------------------
// Inter-chunk scan: prevb[c] = bf16(carry); carry = carry*cd + states[c]
// ---------------------------------------------------------------------------
__global__ __launch_bounds__(256) void k_scan(
    const float* __restrict__ states, const float* __restrict__ cd_t,
    bf16* __restrict__ prevb){
  int b = blockIdx.x >> 4, h = blockIdx.x & 15;
  int tid = threadIdx.x;
  float carry[32];
  #pragma unroll
  for (int i=0;i<32;i++) carry[i]=0.f;
  for (int c=0;c<NC;c++){
    size_t base = ((size_t)(b*256 + c*16 + h))*HEADDIM*D_STATE;
    float cd = cd_t[(b*NHEADS+h)*NC + c];
    #pragma unroll
    for (int i=0;i<32;i++){
      size_t idx = base + (size_t)i*256 + tid;
      prevb[idx] = __float2bfloat16(carry[i]);
      carry[i] = carry[i]*cd + states[idx];
    }
  }
}

// ---------------------------------------------------------------------------
// y[q, h*128+p] += exp(acum[q]) * sum_n C[q,n]*prev[h][p,n]   (MFMA)
// ---------------------------------------------------------------------------
__global__ __launch_bounds__(256,2) void k_yoff(
    const bf16* __restrict__ xbc, const bf16* __restrict__ prevb,
    const float* __restrict__ acum_t, bf16* __restrict__ y){
  const int bid = blockIdx.x;
  const int h = bid & 15, c = (bid>>4)&15, b = bid>>8;
  const int z = b*NC + c;
  const int tid = threadIdx.x;
  const int w = tid >> 6, l = tid & 63;
  const int quad = l >> 4, lq = l & 15;
  const bf16* Crow = xbc + (size_t)z*CHUNK*CONV_DIM + D_INNER + D_STATE;
  const bf16* pv = prevb + (size_t)bid*HEADDIM*D_STATE;
  const float* acum = acum_t + ((size_t)(b*NHEADS+h))*LEN + c*CHUNK;
  const int qw = w*64;
  f32x4 acc[4][8] = {};
  #pragma unroll
  for (int s=0;s<2;s++){
    bf16x8 bp[8];
    #pragma unroll
    for (int pn=0;pn<8;pn++)
      bp[pn] = *(const bf16x8*)(pv + (pn*16+lq)*D_STATE + s*32 + quad*8);
    #pragma unroll
    for (int qm=0;qm<4;qm++){
      int row = qw + qm*16 + lq;
      float e = __expf(acum[row]);
      bf16x8 a = *(const bf16x8*)(Crow + (size_t)row*CONV_DIM + s*32 + quad*8);
      bf16x8 ae;
      #pragma unroll
      for (int j=0;j<8;j++) ae[j] = (__bf16)((float)a[j] * e);
      #pragma unroll
      for (int pn=0;pn<8;pn++)
        acc[qm][pn] = __builtin_amdgcn_mfma_f32_16x16x32_bf16(ae, bp[pn], acc[qm][pn], 0,0,0);
    }
  }
  bf16* yrow = y + (size_t)z*CHUNK*D_INNER + h*HEADDIM;
  #pragma unroll
  for (int qm=0;qm<4;qm++)
    #pragma unroll
    for (int pn=0;pn<8;pn++)
      #pragma unroll
      for (int i=0;i<4;i++){
        int q = qw + qm*16 + quad*4 + i;
        int p = pn*16 + lq;
        bf16* yp = &yrow[(size_t)q*D_INNER + p];
        storeF(yp, toF(*yp) + acc[qm][pn][i]);
      }
}

// ---------------------------------------------------------------------------
// y = y * silu(z); y = y * rsqrt(mean(y^2)+eps) * norm_w   (in place, bf16)
// ---------------------------------------------------------------------------
__global__ __launch_bounds__(256) void k_gatenorm(
    const bf16* __restrict__ zxbct, const float* __restrict__ norm_w,
    bf16* __restrict__ y){
  int m = blockIdx.x;
  const bf16* zrow = zxbct + (size_t)m*ZPAD;
  bf16* yrow = y + (size_t)m*D_INNER;
  float v[8]; float ss = 0.f;
  #pragma unroll
  for (int i=0;i<8;i++){
    int e = threadIdx.x + i*256;
    float z = toF(zrow[e]);
    float val = toF(yrow[e]) * fsilu(z);
    v[i] = val; ss += val*val;
  }
  #pragma unroll
  for (int off=32; off>0; off>>=1) ss += __shfl_down(ss, off, 64);
  __shared__ float red[4];
  if ((threadIdx.x & 63) == 0) red[threadIdx.x >> 6] = ss;
  __syncthreads();
  float tot = red[0]+red[1]+red[2]+red[3];
  float r = rsqrtf(tot * (1.f/D_INNER) + 1e-5f);
  #pragma unroll
  for (int i=0;i<8;i++){
    int e = threadIdx.x + i*256;
    storeF(&yrow[e], v[i] * r * norm_w[e]);
  }
}

extern "C" void kernel_launch(void* const* d_in, const int* in_sizes, int n_in,
                              void* d_out, int out_size, void* d_ws, size_t ws_size,
                              hipStream_t stream) {
  const float* u         = (const float*)d_in[0];
  const float* in_proj_w = (const float*)d_in[1];
  const float* conv_w    = (const float*)d_in[2];
  const float* conv_b    = (const float*)d_in[3];
  const float* dt_bias   = (const float*)d_in[4];
  const float* A_log     = (const float*)d_in[5];
  const float* Dp        = (const float*)d_in[6];
  const float* norm_w    = (const float*)d_in[7];
  const float* out_proj_w= (const float*)d_in[8];
  float* out = (float*)d_out;

  char* p = (char*)d_ws;
  auto alloc = [&](size_t bytes){ char* r = p; p += (bytes + 255) & ~size_t(255); return r; };
  bf16*  zxbct = (bf16*) alloc((size_t)MROWS*ZPAD*2);                    //  71.3 MB
  bf16*  xbc   = (bf16*) alloc((size_t)MROWS*CONV_DIM*2);                //  35.7 MB
  bf16*  y     = (bf16*) alloc((size_t)MROWS*D_INNER*2);                 //  33.6 MB
  bf16*  ub    = (bf16*) alloc((size_t)MROWS*D_MODEL*2);                 //  16.8 MB (alias: states)
  bf16*  Wb_in = (bf16*) alloc((size_t)ZPAD*D_MODEL*2);                  //   8.9 MB (alias: prevb)
  bf16*  Wb_out= (bf16*) alloc((size_t)D_MODEL*D_INNER*2);               //   4.2 MB
  float* dt_t  = (float*)alloc((size_t)NB*NHEADS*LEN*4);                 //   0.5 MB
  float* acum_t= (float*)alloc((size_t)NB*NHEADS*LEN*4);                 //   0.5 MB
  float* cd_t  = (float*)alloc((size_t)NB*NHEADS*NC*4);                  //   tiny
  float* states= (float*)ub;     // 16.8 MB, live after in_proj GEMM
  bf16*  prevb = (bf16*)Wb_in;   //  8.4 MB, live after in_proj GEMM
  // total ~171.5 MB

  dim3 blk(256);
  k_tobf16<<<dim3((MROWS*D_MODEL+255)/256), blk, 0, stream>>>(u, ub, MROWS*D_MODEL);
  k_padW  <<<dim3((ZPAD*D_MODEL)/256), blk, 0, stream>>>(in_proj_w, Wb_in);
  k_tobf16<<<dim3((D_MODEL*D_INNER+255)/256), blk, 0, stream>>>(out_proj_w, Wb_out, D_MODEL*D_INNER);

  k_gemm_mfma<bf16><<<dim3(MROWS/128, ZPAD/128), blk, 0, stream>>>(
      ub, D_MODEL, Wb_in, D_MODEL, zxbct, ZPAD, D_MODEL);

  k_dt   <<<dim3(NB*NC*NHEADS), blk, 0, stream>>>(zxbct, dt_bias, A_log, dt_t, acum_t, cd_t);
  k_conv <<<dim3((MROWS*(CONV_DIM/8))/256), blk, 0, stream>>>(zxbct, conv_w, conv_b, xbc);
  k_fused<<<dim3(NB*NC*NHEADS), blk, 0, stream>>>(xbc, acum_t, dt_t, Dp, y, states);
  k_scan <<<dim3(NB*NHEADS), blk, 0, stream>>>(states, cd_t, prevb);
  k_yoff <<<dim3(NB*NC*NHEADS), blk, 0, stream>>>(xbc, prevb, acum_t, y);
  k_gatenorm<<<dim3(MROWS), blk, 0, stream>>>(zxbct, norm_w, y);

  k_gemm_mfma<float><<<dim3(MROWS/128, D_MODEL/128), blk, 0, stream>>>(
      y, D_INNER, Wb_out, D_INNER, out, D_MODEL, D_INNER);
}

// Round 5
// 439.375 us; speedup vs baseline: 5.4912x; 1.2087x over previous
//
#include <hip/hip_runtime.h>
#include <hip/hip_bf16.h>
#include <cstdint>
#include <cstddef>

#define D_MODEL   1024
#define D_INNER   2048
#define D_STATE   64
#define HEADDIM   128
#define NHEADS    16
#define D_CONV    4
#define CHUNK     256
#define D_IN_PROJ 4240     // 2*D_INNER + 2*D_STATE + NHEADS
#define ZPAD      4352     // padded for MFMA tiles
#define CONV_DIM  2176     // D_INNER + 2*D_STATE
#define NB        2
#define LEN       4096
#define NC        16
#define MROWS     (NB*LEN) // 8192

typedef __hip_bfloat16 bf16;
typedef __bf16 bf16x8 __attribute__((ext_vector_type(8)));
typedef float  f32x4  __attribute__((ext_vector_type(4)));

__device__ __forceinline__ float fsilu(float x){ return x / (1.f + __expf(-x)); }
__device__ __forceinline__ float toF(float x){ return x; }
__device__ __forceinline__ float toF(bf16 x){ return __bfloat162float(x); }
__device__ __forceinline__ void storeF(float* p, float v){ *p = v; }
__device__ __forceinline__ void storeF(bf16* p, float v){ *p = __float2bfloat16(v); }

__device__ __forceinline__ void gload_lds16(const void* g, void* l){
  __builtin_amdgcn_global_load_lds(
     (const __attribute__((address_space(1))) unsigned int*)(uintptr_t)g,
     (__attribute__((address_space(3))) unsigned int*)(uintptr_t)l, 16, 0, 0);
}

// ---------------------------------------------------------------------------
// MFMA bf16 GEMM (m97 structure): C[m,n] = sum_k A[m,k]*B[n,k]
// ---------------------------------------------------------------------------
template<typename TC>
__global__ __launch_bounds__(256) void k_gemm_mfma(
    const bf16* __restrict__ A, int lda,
    const bf16* __restrict__ B, int ldb,
    TC* __restrict__ C, int ldc, int K)
{
  __shared__ __align__(16) bf16 As[128*32];
  __shared__ __align__(16) bf16 Bs[128*32];
  const int tid = threadIdx.x;
  const int w = tid >> 6, l = tid & 63;
  const int m0 = blockIdx.x*128, n0 = blockIdx.y*128;
  const int wm = (w & 1)*64, wn = (w >> 1)*64;
  f32x4 acc[4][4] = {};
  const int sr = l >> 2;
  const int sc = (l & 3)*8;

  for (int k0 = 0; k0 < K; k0 += 32) {
    #pragma unroll
    for (int j = 0; j < 2; j++) {
      const int blk = w*2 + j;
      const int row = blk*16 + sr;
      gload_lds16(A + (size_t)(m0+row)*lda + k0 + sc, (char*)As + blk*1024);
      gload_lds16(B + (size_t)(n0+row)*ldb + k0 + sc, (char*)Bs + blk*1024);
    }
    asm volatile("s_waitcnt vmcnt(0)" ::: "memory");
    __syncthreads();

    const int kq = (l >> 4)*8;
    const int rA = wm + (l & 15);
    const int rB = wn + (l & 15);
    bf16x8 af[4], bfr[4];
    #pragma unroll
    for (int t = 0; t < 4; t++){
      af[t]  = *(const bf16x8*)&As[(rA + t*16)*32 + kq];
      bfr[t] = *(const bf16x8*)&Bs[(rB + t*16)*32 + kq];
    }
    #pragma unroll
    for (int tm = 0; tm < 4; tm++)
      #pragma unroll
      for (int tn = 0; tn < 4; tn++)
        acc[tm][tn] = __builtin_amdgcn_mfma_f32_16x16x32_bf16(af[tm], bfr[tn], acc[tm][tn], 0,0,0);
    __syncthreads();
  }

  const int col   = n0 + wn + (l & 15);
  const int rbase = m0 + wm + (l >> 4)*4;
  #pragma unroll
  for (int tm = 0; tm < 4; tm++)
    #pragma unroll
    for (int tn = 0; tn < 4; tn++)
      #pragma unroll
      for (int i = 0; i < 4; i++){
        int r = rbase + tm*16 + i;
        storeF(&C[(size_t)r*ldc + (col + tn*16)], acc[tm][tn][i]);
      }
}

// ---------------------------------------------------------------------------
// conversions
// ---------------------------------------------------------------------------
__global__ __launch_bounds__(256) void k_tobf16(
    const float* __restrict__ src, bf16* __restrict__ dst, int n){
  int i = blockIdx.x*256 + threadIdx.x;
  if (i < n) dst[i] = __float2bfloat16(src[i]);
}

__global__ __launch_bounds__(256) void k_padW(
    const float* __restrict__ W, bf16* __restrict__ Wb){
  int i = blockIdx.x*256 + threadIdx.x;
  int r = i >> 10;
  Wb[i] = __float2bfloat16((r < D_IN_PROJ) ? W[i] : 0.f);
}

// ---------------------------------------------------------------------------
// dt = softplus(dt_raw + dt_bias); a = dt*A; inclusive cumsum over chunk.
// ---------------------------------------------------------------------------
__global__ __launch_bounds__(256) void k_dt(
    const bf16* __restrict__ zxbct, const float* __restrict__ dt_bias,
    const float* __restrict__ A_log, float* __restrict__ dt_t,
    float* __restrict__ acum_t, float* __restrict__ cd_t){
  int bid = blockIdx.x;
  int h = bid & 15, c = (bid>>4)&15, b = bid>>8;
  int q = threadIdx.x;
  size_t m = (size_t)(b*NC + c)*CHUNK + q;
  float x = toF(zxbct[m*ZPAD + (D_INNER + CONV_DIM) + h]) + dt_bias[h];
  float dtv = (x > 20.f) ? x : log1pf(__expf(x));
  float Ah = -__expf(A_log[h]);
  float a = dtv * Ah;
  __shared__ float sb[CHUNK];
  sb[q] = a;
  __syncthreads();
  #pragma unroll
  for (int off=1; off<CHUNK; off<<=1){
    float t = (q >= off) ? sb[q-off] : 0.f;
    __syncthreads();
    sb[q] += t;
    __syncthreads();
  }
  float ac = sb[q];
  size_t o = ((size_t)(b*NHEADS+h))*LEN + c*CHUNK + q;
  dt_t[o]   = dtv;
  acum_t[o] = ac;
  if (q == CHUNK-1) cd_t[(b*NHEADS+h)*NC + c] = __expf(ac);
}

// ---------------------------------------------------------------------------
// Depthwise causal conv (4 taps) + SiLU, LDS-staged.
// Block: 64 channels x 32 time rows.  Grid: (CONV_DIM/64, MROWS/32).
// ---------------------------------------------------------------------------
__global__ __launch_bounds__(256) void k_conv(
    const bf16* __restrict__ zxbct, const float* __restrict__ conv_w,
    const float* __restrict__ conv_b, bf16* __restrict__ xbc){
  __shared__ __align__(16) __bf16 xs[35*64];
  __shared__ __align__(16) float  ws[64*4];
  __shared__ float bs[64];
  const int tid = threadIdx.x;
  const int cq = tid & 7;          // channel octet (8 ch) within 64
  const int tm = tid >> 3;         // 0..31 time row
  const int c0 = blockIdx.x*64;
  const int m0 = blockIdx.y*32;

  // stage x rows m0-3 .. m0+31 (35 rows x 64 ch)
  {
    int g = m0 - 3 + tm; if (g < 0) g = 0;
    *(bf16x8*)&xs[tm*64 + cq*8] =
        *(const bf16x8*)(zxbct + (size_t)g*ZPAD + D_INNER + c0 + cq*8);
    if (tid < 24){
      int r2 = 32 + (tid >> 3);
      int g2 = m0 - 3 + r2;
      *(bf16x8*)&xs[r2*64 + cq*8] =
          *(const bf16x8*)(zxbct + (size_t)g2*ZPAD + D_INNER + c0 + cq*8);
    }
  }
  if (tid < 64)      *(float4*)&ws[tid*4] = *(const float4*)(conv_w + (size_t)(c0+tid)*4);
  else if (tid < 128) bs[tid-64] = conv_b[c0 + tid - 64];
  __syncthreads();

  const int m = m0 + tm;
  const int l = m & (LEN-1);
  float acc[8];
  #pragma unroll
  for (int j=0;j<8;j++) acc[j] = bs[cq*8+j];
  #pragma unroll
  for (int w=0; w<D_CONV; w++){
    if (l - (D_CONV-1) + w >= 0){
      bf16x8 v = *(const bf16x8*)&xs[(tm+w)*64 + cq*8];
      #pragma unroll
      for (int j=0;j<8;j++) acc[j] += (float)v[j] * ws[(cq*8+j)*4 + w];
    }
  }
  bf16x8 o;
  #pragma unroll
  for (int j=0;j<8;j++) o[j] = (__bf16)fsilu(acc[j]);
  *(bf16x8*)(xbc + (size_t)m*CONV_DIM + c0 + cq*8) = o;
}

// ---------------------------------------------------------------------------
// FUSED per (b,c,h): scores (MFMA) -> coef+mask+Dp -> y_diag (MFMA),
// plus chunk states (MFMA).
// ---------------------------------------------------------------------------
__global__ __launch_bounds__(256,2) void k_fused(
    const bf16* __restrict__ xbc, const float* __restrict__ acum_t,
    const float* __restrict__ dt_t, const float* __restrict__ Dp,
    bf16* __restrict__ y, float* __restrict__ states)
{
  const int bid = blockIdx.x;
  const int h = bid & 15, c = (bid>>4)&15, b = bid>>8;
  const int z = b*NC + c;
  const int tid = threadIdx.x;
  const int w = tid >> 6, l = tid & 63;
  const int quad = l >> 4, lq = l & 15;

  __shared__ __align__(16) __bf16 xsT[128*72];   // xsT[p][k], pad 72
  __shared__ __align__(16) __bf16 bts[64*72];    // bts[n][k] = B[k][n]*w[k]
  __shared__ __align__(16) __bf16 Ms[4][64*72];  // per-wave M tile [q][k]
  __shared__ float acs[CHUNK];

  const float* acum = acum_t + ((size_t)(b*NHEADS+h))*LEN + c*CHUNK;
  const float* dtc  = dt_t   + ((size_t)(b*NHEADS+h))*LEN + c*CHUNK;
  const float alast = acum[CHUNK-1];
  acs[tid] = acum[tid];

  const bf16* xrow = xbc + (size_t)z*CHUNK*CONV_DIM + h*HEADDIM;
  const bf16* Brow = xbc + (size_t)z*CHUNK*CONV_DIM + D_INNER;
  const bf16* Crow = xbc + (size_t)z*CHUNK*CONV_DIM + D_INNER + D_STATE;
  const float Dph = Dp[h];
  const int qw = w*64;

  f32x4 Yacc[4][8] = {};
  f32x4 Sst[2][4]  = {};

  for (int t = 0; t < 4; t++){
    const int k0 = t*64;
    __syncthreads();
    {
      const bf16* xr = xrow + (size_t)(k0+l)*CONV_DIM;
      #pragma unroll
      for (int pass=0; pass<4; pass++){
        int pb = w*8 + pass*32;
        bf16x8 v = *(const bf16x8*)(xr + pb);
        #pragma unroll
        for (int j=0;j<8;j++) xsT[(pb+j)*72 + l] = v[j];
      }
      float wl = dtc[k0+l] * __expf(alast - acum[k0+l]);
      const bf16* br = Brow + (size_t)(k0+l)*CONV_DIM;
      #pragma unroll
      for (int pass=0; pass<2; pass++){
        int nb = w*8 + pass*32;
        bf16x8 v = *(const bf16x8*)(br + nb);
        #pragma unroll
        for (int j=0;j<8;j++) bts[(nb+j)*72 + l] = (__bf16)((float)v[j] * wl);
      }
    }
    __syncthreads();

    #pragma unroll
    for (int s=0;s<2;s++){
      bf16x8 bf_[4];
      #pragma unroll
      for (int ni=0;ni<4;ni++)
        bf_[ni] = *(const bf16x8*)&bts[(ni*16+lq)*72 + s*32 + quad*8];
      #pragma unroll
      for (int mi=0;mi<2;mi++){
        bf16x8 a = *(const bf16x8*)&xsT[(w*32 + mi*16 + lq)*72 + s*32 + quad*8];
        #pragma unroll
        for (int ni=0;ni<4;ni++)
          Sst[mi][ni] = __builtin_amdgcn_mfma_f32_16x16x32_bf16(a, bf_[ni], Sst[mi][ni], 0,0,0);
      }
    }

    if (t <= w){
      float dk4[4], ak4[4];
      #pragma unroll
      for (int kn=0;kn<4;kn++){
        int kl = k0 + kn*16 + lq;
        dk4[kn] = dtc[kl];
        ak4[kn] = acs[kl];
      }
      #pragma unroll
      for (int qm=0;qm<4;qm++){
        f32x4 Sacc[4] = {};
        #pragma unroll
        for (int s=0;s<2;s++){
          bf16x8 af = *(const bf16x8*)(Crow + (size_t)(qw+qm*16+lq)*CONV_DIM + s*32 + quad*8);
          #pragma unroll
          for (int kn=0;kn<4;kn++){
            bf16x8 bf_ = *(const bf16x8*)(Brow + (size_t)(k0+kn*16+lq)*CONV_DIM + s*32 + quad*8);
            Sacc[kn] = __builtin_amdgcn_mfma_f32_16x16x32_bf16(af, bf_, Sacc[kn], 0,0,0);
          }
        }
        float aq4[4];
        #pragma unroll
        for (int i=0;i<4;i++) aq4[i] = acs[qw+qm*16+quad*4+i];
        #pragma unroll
        for (int kn=0;kn<4;kn++)
          #pragma unroll
          for (int i=0;i<4;i++){
            int ql = qw + qm*16 + quad*4 + i;
            int kl = k0 + kn*16 + lq;
            float v = Sacc[kn][i] * __expf(aq4[i]-ak4[kn]) * dk4[kn];
            v = (kl < ql) ? v : ((kl == ql) ? v + Dph : 0.f);
            Ms[w][(qm*16+quad*4+i)*72 + kn*16+lq] = (__bf16)v;
          }
      }
      asm volatile("s_waitcnt lgkmcnt(0)" ::: "memory");
      #pragma unroll
      for (int s2=0;s2<2;s2++){
        bf16x8 bp[8];
        #pragma unroll
        for (int pn=0;pn<8;pn++)
          bp[pn] = *(const bf16x8*)&xsT[(pn*16+lq)*72 + s2*32 + quad*8];
        #pragma unroll
        for (int qm=0;qm<4;qm++){
          bf16x8 am = *(const bf16x8*)&Ms[w][(qm*16+lq)*72 + s2*32 + quad*8];
          #pragma unroll
          for (int pn=0;pn<8;pn++)
            Yacc[qm][pn] = __builtin_amdgcn_mfma_f32_16x16x32_bf16(am, bp[pn], Yacc[qm][pn], 0,0,0);
        }
      }
    }
  }

  bf16* yrow = y + (size_t)z*CHUNK*D_INNER + h*HEADDIM;
  #pragma unroll
  for (int qm=0;qm<4;qm++)
    #pragma unroll
    for (int pn=0;pn<8;pn++)
      #pragma unroll
      for (int i=0;i<4;i++){
        int q = qw + qm*16 + quad*4 + i;
        int p = pn*16 + lq;
        storeF(&yrow[(size_t)q*D_INNER + p], Yacc[qm][pn][i]);
      }
  float* so = states + (size_t)bid*HEADDIM*D_STATE;
  #pragma unroll
  for (int mi=0;mi<2;mi++)
    #pragma unroll
    for (int ni=0;ni<4;ni++)
      #pragma unroll
      for (int i=0;i<4;i++){
        int pp = w*32 + mi*16 + quad*4 + i;
        int n = ni*16 + lq;
        so[pp*D_STATE + n] = Sst[mi][ni][i];
      }
}

// ---------------------------------------------------------------------------
// Inter-chunk scan: prevb[c] = bf16(carry); carry = carry*cd + states[c]
// grid (32, 8): blockIdx.y = p-tile.  4 carried elems/thread.
// ---------------------------------------------------------------------------
__global__ __launch_bounds__(256) void k_scan(
    const float* __restrict__ states, const float* __restrict__ cd_t,
    bf16* __restrict__ prevb){
  int b = blockIdx.x >> 4, h = blockIdx.x & 15;
  int pt = blockIdx.y;
  int tid = threadIdx.x;
  float carry[4] = {0.f,0.f,0.f,0.f};
  for (int c=0;c<NC;c++){
    size_t base = ((size_t)(b*256 + c*16 + h))*HEADDIM*D_STATE + (size_t)pt*1024;
    float cd = cd_t[(b*NHEADS+h)*NC + c];
    #pragma unroll
    for (int i=0;i<4;i++){
      size_t idx = base + (size_t)i*256 + tid;
      prevb[idx] = __float2bfloat16(carry[i]);
      carry[i] = carry[i]*cd + states[idx];
    }
  }
}

// ---------------------------------------------------------------------------
// y[q, h*128+p] += exp(acum[q]) * sum_n C[q,n]*prev[h][p,n]   (MFMA)
// ---------------------------------------------------------------------------
__global__ __launch_bounds__(256,2) void k_yoff(
    const bf16* __restrict__ xbc, const bf16* __restrict__ prevb,
    const float* __restrict__ acum_t, bf16* __restrict__ y){
  const int bid = blockIdx.x;
  const int h = bid & 15, c = (bid>>4)&15, b = bid>>8;
  const int z = b*NC + c;
  const int tid = threadIdx.x;
  const int w = tid >> 6, l = tid & 63;
  const int quad = l >> 4, lq = l & 15;
  const bf16* Crow = xbc + (size_t)z*CHUNK*CONV_DIM + D_INNER + D_STATE;
  const bf16* pv = prevb + (size_t)bid*HEADDIM*D_STATE;
  const float* acum = acum_t + ((size_t)(b*NHEADS+h))*LEN + c*CHUNK;
  const int qw = w*64;
  f32x4 acc[4][8] = {};
  #pragma unroll
  for (int s=0;s<2;s++){
    bf16x8 bp[8];
    #pragma unroll
    for (int pn=0;pn<8;pn++)
      bp[pn] = *(const bf16x8*)(pv + (pn*16+lq)*D_STATE + s*32 + quad*8);
    #pragma unroll
    for (int qm=0;qm<4;qm++){
      int row = qw + qm*16 + lq;
      float e = __expf(acum[row]);
      bf16x8 a = *(const bf16x8*)(Crow + (size_t)row*CONV_DIM + s*32 + quad*8);
      bf16x8 ae;
      #pragma unroll
      for (int j=0;j<8;j++) ae[j] = (__bf16)((float)a[j] * e);
      #pragma unroll
      for (int pn=0;pn<8;pn++)
        acc[qm][pn] = __builtin_amdgcn_mfma_f32_16x16x32_bf16(ae, bp[pn], acc[qm][pn], 0,0,0);
    }
  }
  bf16* yrow = y + (size_t)z*CHUNK*D_INNER + h*HEADDIM;
  #pragma unroll
  for (int qm=0;qm<4;qm++)
    #pragma unroll
    for (int pn=0;pn<8;pn++)
      #pragma unroll
      for (int i=0;i<4;i++){
        int q = qw + qm*16 + quad*4 + i;
        int p = pn*16 + lq;
        bf16* yp = &yrow[(size_t)q*D_INNER + p];
        storeF(yp, toF(*yp) + acc[qm][pn][i]);
      }
}

// ---------------------------------------------------------------------------
// y = y * silu(z); y = y * rsqrt(mean(y^2)+eps) * norm_w   (in place, bf16)
// vectorized: one bf16x8 per thread.
// ---------------------------------------------------------------------------
__global__ __launch_bounds__(256) void k_gatenorm(
    const bf16* __restrict__ zxbct, const float* __restrict__ norm_w,
    bf16* __restrict__ y){
  int m = blockIdx.x;
  int e0 = threadIdx.x*8;
  bf16x8 zv = *(const bf16x8*)(zxbct + (size_t)m*ZPAD + e0);
  bf16x8 yv = *(const bf16x8*)(y + (size_t)m*D_INNER + e0);
  float4 nw0 = *(const float4*)(norm_w + e0);
  float4 nw1 = *(const float4*)(norm_w + e0 + 4);
  float v[8]; float ss = 0.f;
  #pragma unroll
  for (int j=0;j<8;j++){
    float val = (float)yv[j] * fsilu((float)zv[j]);
    v[j] = val; ss += val*val;
  }
  #pragma unroll
  for (int off=32; off>0; off>>=1) ss += __shfl_down(ss, off, 64);
  __shared__ float red[4];
  if ((threadIdx.x & 63) == 0) red[threadIdx.x >> 6] = ss;
  __syncthreads();
  float tot = red[0]+red[1]+red[2]+red[3];
  float r = rsqrtf(tot * (1.f/D_INNER) + 1e-5f);
  float nw[8] = {nw0.x,nw0.y,nw0.z,nw0.w,nw1.x,nw1.y,nw1.z,nw1.w};
  bf16x8 o;
  #pragma unroll
  for (int j=0;j<8;j++) o[j] = (__bf16)(v[j] * r * nw[j]);
  *(bf16x8*)(y + (size_t)m*D_INNER + e0) = o;
}

extern "C" void kernel_launch(void* const* d_in, const int* in_sizes, int n_in,
                              void* d_out, int out_size, void* d_ws, size_t ws_size,
                              hipStream_t stream) {
  const float* u         = (const float*)d_in[0];
  const float* in_proj_w = (const float*)d_in[1];
  const float* conv_w    = (const float*)d_in[2];
  const float* conv_b    = (const float*)d_in[3];
  const float* dt_bias   = (const float*)d_in[4];
  const float* A_log     = (const float*)d_in[5];
  const float* Dp        = (const float*)d_in[6];
  const float* norm_w    = (const float*)d_in[7];
  const float* out_proj_w= (const float*)d_in[8];
  float* out = (float*)d_out;

  char* p = (char*)d_ws;
  auto alloc = [&](size_t bytes){ char* r = p; p += (bytes + 255) & ~size_t(255); return r; };
  bf16*  zxbct = (bf16*) alloc((size_t)MROWS*ZPAD*2);                    //  71.3 MB
  bf16*  xbc   = (bf16*) alloc((size_t)MROWS*CONV_DIM*2);                //  35.7 MB
  bf16*  y     = (bf16*) alloc((size_t)MROWS*D_INNER*2);                 //  33.6 MB
  bf16*  ub    = (bf16*) alloc((size_t)MROWS*D_MODEL*2);                 //  16.8 MB (alias: states)
  bf16*  Wb_in = (bf16*) alloc((size_t)ZPAD*D_MODEL*2);                  //   8.9 MB (alias: prevb)
  bf16*  Wb_out= (bf16*) alloc((size_t)D_MODEL*D_INNER*2);               //   4.2 MB
  float* dt_t  = (float*)alloc((size_t)NB*NHEADS*LEN*4);                 //   0.5 MB
  float* acum_t= (float*)alloc((size_t)NB*NHEADS*LEN*4);                 //   0.5 MB
  float* cd_t  = (float*)alloc((size_t)NB*NHEADS*NC*4);                  //   tiny
  float* states= (float*)ub;     // 16.8 MB, live after in_proj GEMM
  bf16*  prevb = (bf16*)Wb_in;   //  8.4 MB, live after in_proj GEMM
  // total ~171.5 MB

  dim3 blk(256);
  k_tobf16<<<dim3((MROWS*D_MODEL+255)/256), blk, 0, stream>>>(u, ub, MROWS*D_MODEL);
  k_padW  <<<dim3((ZPAD*D_MODEL)/256), blk, 0, stream>>>(in_proj_w, Wb_in);
  k_tobf16<<<dim3((D_MODEL*D_INNER+255)/256), blk, 0, stream>>>(out_proj_w, Wb_out, D_MODEL*D_INNER);

  k_gemm_mfma<bf16><<<dim3(MROWS/128, ZPAD/128), blk, 0, stream>>>(
      ub, D_MODEL, Wb_in, D_MODEL, zxbct, ZPAD, D_MODEL);

  k_dt   <<<dim3(NB*NC*NHEADS), blk, 0, stream>>>(zxbct, dt_bias, A_log, dt_t, acum_t, cd_t);
  k_conv <<<dim3(CONV_DIM/64, MROWS/32), blk, 0, stream>>>(zxbct, conv_w, conv_b, xbc);
  k_fused<<<dim3(NB*NC*NHEADS), blk, 0, stream>>>(xbc, acum_t, dt_t, Dp, y, states);
  k_scan <<<dim3(NB*NHEADS, 8), blk, 0, stream>>>(states, cd_t, prevb);
  k_yoff <<<dim3(NB*NC*NHEADS), blk, 0, stream>>>(xbc, prevb, acum_t, y);
  k_gatenorm<<<dim3(MROWS), blk, 0, stream>>>(zxbct, norm_w, y);

  k_gemm_mfma<float><<<dim3(MROWS/128, D_MODEL/128), blk, 0, stream>>>(
      y, D_INNER, Wb_out, D_INNER, out, D_MODEL, D_INNER);
}

// Round 6
// 422.961 us; speedup vs baseline: 5.7044x; 1.0388x over previous
//
#include <hip/hip_runtime.h>
#include <hip/hip_bf16.h>
#include <cstdint>
#include <cstddef>

#define D_MODEL   1024
#define D_INNER   2048
#define D_STATE   64
#define HEADDIM   128
#define NHEADS    16
#define D_CONV    4
#define CHUNK     256
#define D_IN_PROJ 4240     // 2*D_INNER + 2*D_STATE + NHEADS
#define ZPAD      4352     // padded for MFMA tiles
#define CONV_DIM  2176     // D_INNER + 2*D_STATE
#define NB        2
#define LEN       4096
#define NC        16
#define MROWS     (NB*LEN) // 8192

typedef __hip_bfloat16 bf16;
typedef __bf16 bf16x8 __attribute__((ext_vector_type(8)));
typedef float  f32x4  __attribute__((ext_vector_type(4)));
typedef unsigned short us4 __attribute__((ext_vector_type(4)));

__device__ __forceinline__ float fsilu(float x){ return x / (1.f + __expf(-x)); }
__device__ __forceinline__ float toF(float x){ return x; }
__device__ __forceinline__ float toF(bf16 x){ return __bfloat162float(x); }
__device__ __forceinline__ void storeF(float* p, float v){ *p = v; }
__device__ __forceinline__ void storeF(bf16* p, float v){ *p = __float2bfloat16(v); }

__device__ __forceinline__ unsigned short f2bs(float v){
  return __bfloat16_as_ushort(__float2bfloat16(v));
}
// store 4 consecutive elems (cols) from one f32x4
__device__ __forceinline__ void store4(bf16* p, f32x4 v){
  us4 o; o[0]=f2bs(v[0]); o[1]=f2bs(v[1]); o[2]=f2bs(v[2]); o[3]=f2bs(v[3]);
  *(us4*)p = o;
}
__device__ __forceinline__ void store4(float* p, f32x4 v){
  *(f32x4*)p = v;
}

__device__ __forceinline__ void gload_lds16(const void* g, void* l){
  __builtin_amdgcn_global_load_lds(
     (const __attribute__((address_space(1))) unsigned int*)(uintptr_t)g,
     (__attribute__((address_space(3))) unsigned int*)(uintptr_t)l, 16, 0, 0);
}

// ---------------------------------------------------------------------------
// MFMA bf16 GEMM (m97 structure): C[m,n] = sum_k A[m,k]*B[n,k]
// Operand-swapped epilogue: lane holds 4 consecutive cols of one row.
// ---------------------------------------------------------------------------
template<typename TC>
__global__ __launch_bounds__(256) void k_gemm_mfma(
    const bf16* __restrict__ A, int lda,
    const bf16* __restrict__ B, int ldb,
    TC* __restrict__ C, int ldc, int K)
{
  __shared__ __align__(16) bf16 As[128*32];
  __shared__ __align__(16) bf16 Bs[128*32];
  const int tid = threadIdx.x;
  const int w = tid >> 6, l = tid & 63;
  const int quad = l >> 4, lq = l & 15;
  const int m0 = blockIdx.x*128, n0 = blockIdx.y*128;
  const int wm = (w & 1)*64, wn = (w >> 1)*64;
  f32x4 acc[4][4] = {};
  const int sr = l >> 2;
  const int sc = (l & 3)*8;

  for (int k0 = 0; k0 < K; k0 += 32) {
    #pragma unroll
    for (int j = 0; j < 2; j++) {
      const int blk = w*2 + j;
      const int row = blk*16 + sr;
      gload_lds16(A + (size_t)(m0+row)*lda + k0 + sc, (char*)As + blk*1024);
      gload_lds16(B + (size_t)(n0+row)*ldb + k0 + sc, (char*)Bs + blk*1024);
    }
    asm volatile("s_waitcnt vmcnt(0)" ::: "memory");
    __syncthreads();

    const int kq = quad*8;
    const int rA = wm + lq;
    const int rB = wn + lq;
    bf16x8 af[4], bfr[4];
    #pragma unroll
    for (int t = 0; t < 4; t++){
      af[t]  = *(const bf16x8*)&As[(rA + t*16)*32 + kq];
      bfr[t] = *(const bf16x8*)&Bs[(rB + t*16)*32 + kq];
    }
    // swapped: A-op = B rows (cols), B-op = A rows (rows)
    #pragma unroll
    for (int tm = 0; tm < 4; tm++)
      #pragma unroll
      for (int tn = 0; tn < 4; tn++)
        acc[tm][tn] = __builtin_amdgcn_mfma_f32_16x16x32_bf16(bfr[tn], af[tm], acc[tm][tn], 0,0,0);
    __syncthreads();
  }

  // D[m'=col: quad*4+i][n'=row: lq]
  #pragma unroll
  for (int tm = 0; tm < 4; tm++){
    int r = m0 + wm + tm*16 + lq;
    #pragma unroll
    for (int tn = 0; tn < 4; tn++){
      int cb = n0 + wn + tn*16 + quad*4;
      store4(&C[(size_t)r*ldc + cb], acc[tm][tn]);
    }
  }
}

// ---------------------------------------------------------------------------
// conversions
// ---------------------------------------------------------------------------
__global__ __launch_bounds__(256) void k_tobf16(
    const float* __restrict__ src, bf16* __restrict__ dst, int n){
  int i = blockIdx.x*256 + threadIdx.x;
  if (i < n) dst[i] = __float2bfloat16(src[i]);
}

__global__ __launch_bounds__(256) void k_padW(
    const float* __restrict__ W, bf16* __restrict__ Wb){
  int i = blockIdx.x*256 + threadIdx.x;
  int r = i >> 10;
  Wb[i] = __float2bfloat16((r < D_IN_PROJ) ? W[i] : 0.f);
}

// ---------------------------------------------------------------------------
// dt = softplus(dt_raw + dt_bias); a = dt*A; inclusive cumsum over chunk.
// ---------------------------------------------------------------------------
__global__ __launch_bounds__(256) void k_dt(
    const bf16* __restrict__ zxbct, const float* __restrict__ dt_bias,
    const float* __restrict__ A_log, float* __restrict__ dt_t,
    float* __restrict__ acum_t, float* __restrict__ cd_t){
  int bid = blockIdx.x;
  int h = bid & 15, c = (bid>>4)&15, b = bid>>8;
  int q = threadIdx.x;
  size_t m = (size_t)(b*NC + c)*CHUNK + q;
  float x = toF(zxbct[m*ZPAD + (D_INNER + CONV_DIM) + h]) + dt_bias[h];
  float dtv = (x > 20.f) ? x : log1pf(__expf(x));
  float Ah = -__expf(A_log[h]);
  float a = dtv * Ah;
  __shared__ float sb[CHUNK];
  sb[q] = a;
  __syncthreads();
  #pragma unroll
  for (int off=1; off<CHUNK; off<<=1){
    float t = (q >= off) ? sb[q-off] : 0.f;
    __syncthreads();
    sb[q] += t;
    __syncthreads();
  }
  float ac = sb[q];
  size_t o = ((size_t)(b*NHEADS+h))*LEN + c*CHUNK + q;
  dt_t[o]   = dtv;
  acum_t[o] = ac;
  if (q == CHUNK-1) cd_t[(b*NHEADS+h)*NC + c] = __expf(ac);
}

// ---------------------------------------------------------------------------
// Depthwise causal conv (4 taps) + SiLU, LDS-staged.
// ---------------------------------------------------------------------------
__global__ __launch_bounds__(256) void k_conv(
    const bf16* __restrict__ zxbct, const float* __restrict__ conv_w,
    const float* __restrict__ conv_b, bf16* __restrict__ xbc){
  __shared__ __align__(16) __bf16 xs[35*64];
  __shared__ __align__(16) float  ws[64*4];
  __shared__ float bs[64];
  const int tid = threadIdx.x;
  const int cq = tid & 7;
  const int tm = tid >> 3;
  const int c0 = blockIdx.x*64;
  const int m0 = blockIdx.y*32;
  {
    int g = m0 - 3 + tm; if (g < 0) g = 0;
    *(bf16x8*)&xs[tm*64 + cq*8] =
        *(const bf16x8*)(zxbct + (size_t)g*ZPAD + D_INNER + c0 + cq*8);
    if (tid < 24){
      int r2 = 32 + (tid >> 3);
      int g2 = m0 - 3 + r2;
      *(bf16x8*)&xs[r2*64 + cq*8] =
          *(const bf16x8*)(zxbct + (size_t)g2*ZPAD + D_INNER + c0 + cq*8);
    }
  }
  if (tid < 64)      *(float4*)&ws[tid*4] = *(const float4*)(conv_w + (size_t)(c0+tid)*4);
  else if (tid < 128) bs[tid-64] = conv_b[c0 + tid - 64];
  __syncthreads();

  const int m = m0 + tm;
  const int l = m & (LEN-1);
  float acc[8];
  #pragma unroll
  for (int j=0;j<8;j++) acc[j] = bs[cq*8+j];
  #pragma unroll
  for (int w=0; w<D_CONV; w++){
    if (l - (D_CONV-1) + w >= 0){
      bf16x8 v = *(const bf16x8*)&xs[(tm+w)*64 + cq*8];
      #pragma unroll
      for (int j=0;j<8;j++) acc[j] += (float)v[j] * ws[(cq*8+j)*4 + w];
    }
  }
  bf16x8 o;
  #pragma unroll
  for (int j=0;j<8;j++) o[j] = (__bf16)fsilu(acc[j]);
  *(bf16x8*)(xbc + (size_t)m*CONV_DIM + c0 + cq*8) = o;
}

// ---------------------------------------------------------------------------
// FUSED per (b,c,h): scores -> coef+mask+Dp -> y_diag, plus chunk states.
// Balanced causal split: wave w owns q half-tiles j=w and j=7-w (32 rows each),
// 9 causal (32q x 32k) units per wave.  All MFMAs operand-swapped so output
// lanes hold 4 consecutive columns.
// ---------------------------------------------------------------------------
__global__ __launch_bounds__(256,2) void k_fused(
    const bf16* __restrict__ xbc, const float* __restrict__ acum_t,
    const float* __restrict__ dt_t, const float* __restrict__ Dp,
    bf16* __restrict__ y, float* __restrict__ states)
{
  const int bid = blockIdx.x;
  const int h = bid & 15, c = (bid>>4)&15, b = bid>>8;
  const int z = b*NC + c;
  const int tid = threadIdx.x;
  const int w = tid >> 6, l = tid & 63;
  const int quad = l >> 4, lq = l & 15;

  __shared__ __align__(16) __bf16 xsT[128*72];    // [p][k64]
  __shared__ __align__(16) __bf16 bts[64*72];     // [n][k64], w-scaled
  __shared__ __align__(16) __bf16 Ms[4][32*40];   // per-wave coef [q32][k32]
  __shared__ float acs[CHUNK], dts[CHUNK];

  const float* acum = acum_t + ((size_t)(b*NHEADS+h))*LEN + c*CHUNK;
  const float* dtc  = dt_t   + ((size_t)(b*NHEADS+h))*LEN + c*CHUNK;
  const float alast = acum[CHUNK-1];
  acs[tid] = acum[tid];
  dts[tid] = dtc[tid];

  const bf16* xrow = xbc + (size_t)z*CHUNK*CONV_DIM + h*HEADDIM;
  const bf16* Brow = xbc + (size_t)z*CHUNK*CONV_DIM + D_INNER;
  const bf16* Crow = xbc + (size_t)z*CHUNK*CONV_DIM + D_INNER + D_STATE;
  const float Dph = Dp[h];
  const int j0 = w, j1 = 7 - w;

  f32x4 Yacc[2][2][8] = {};   // [half][qm][pn]; lane: q=lq, p=quad*4+i
  f32x4 Sst[2][4]  = {};      // [mi][ni]; lane: p=lq, n=quad*4+i

  for (int t = 0; t < 4; t++){
    const int k0 = t*64;
    __syncthreads();
    {
      const bf16* xr = xrow + (size_t)(k0+l)*CONV_DIM;
      #pragma unroll
      for (int pass=0; pass<4; pass++){
        int pb = w*8 + pass*32;
        bf16x8 v = *(const bf16x8*)(xr + pb);
        #pragma unroll
        for (int j=0;j<8;j++) xsT[(pb+j)*72 + l] = v[j];
      }
      float wl = dts[k0+l] * __expf(alast - acs[k0+l]);
      const bf16* br = Brow + (size_t)(k0+l)*CONV_DIM;
      #pragma unroll
      for (int pass=0; pass<2; pass++){
        int nb = w*8 + pass*32;
        bf16x8 v = *(const bf16x8*)(br + nb);
        #pragma unroll
        for (int j=0;j<8;j++) bts[(nb+j)*72 + l] = (__bf16)((float)v[j] * wl);
      }
    }
    __syncthreads();

    // ---- states: swapped -> A=bts(n rows), B=xsT(p rows)
    #pragma unroll
    for (int s=0;s<2;s++){
      bf16x8 a2[2];
      #pragma unroll
      for (int mi=0;mi<2;mi++)
        a2[mi] = *(const bf16x8*)&xsT[(w*32 + mi*16 + lq)*72 + s*32 + quad*8];
      #pragma unroll
      for (int ni=0;ni<4;ni++){
        bf16x8 bb = *(const bf16x8*)&bts[(ni*16+lq)*72 + s*32 + quad*8];
        #pragma unroll
        for (int mi=0;mi<2;mi++)
          Sst[mi][ni] = __builtin_amdgcn_mfma_f32_16x16x32_bf16(bb, a2[mi], Sst[mi][ni], 0,0,0);
      }
    }

    // ---- causal units
    #pragma unroll
    for (int half=0; half<2; half++){
      const int j = half ? j1 : j0;
      const int qbase = j*32;
      #pragma unroll
      for (int kk=0; kk<2; kk++){
        const int kh = 2*t + kk;
        if (kh > j) continue;
        const int kb32  = kk*32;
        const int kbase = kh*32;
        // scores swapped: A=B(k rows), B=C(q rows) -> D[k=quad*4+i][q=lq]
        f32x4 Sacc[2][2] = {};  // [kn][qm]
        #pragma unroll
        for (int s=0;s<2;s++){
          bf16x8 cf[2], bfk[2];
          #pragma unroll
          for (int qm=0;qm<2;qm++)
            cf[qm] = *(const bf16x8*)(Crow + (size_t)(qbase+qm*16+lq)*CONV_DIM + s*32 + quad*8);
          #pragma unroll
          for (int kn=0;kn<2;kn++)
            bfk[kn] = *(const bf16x8*)(Brow + (size_t)(kbase+kn*16+lq)*CONV_DIM + s*32 + quad*8);
          #pragma unroll
          for (int kn=0;kn<2;kn++)
            #pragma unroll
            for (int qm=0;qm<2;qm++)
              Sacc[kn][qm] = __builtin_amdgcn_mfma_f32_16x16x32_bf16(bfk[kn], cf[qm], Sacc[kn][qm], 0,0,0);
        }
        // coef: lane q = qbase+qm*16+lq; k = kbase+kn*16+quad*4+i
        #pragma unroll
        for (int qm=0;qm<2;qm++){
          int ql = qbase + qm*16 + lq;
          float aq = acs[ql];
          #pragma unroll
          for (int kn=0;kn<2;kn++){
            us4 o;
            #pragma unroll
            for (int i=0;i<4;i++){
              int kl = kbase + kn*16 + quad*4 + i;
              float v = Sacc[kn][qm][i] * __expf(aq - acs[kl]) * dts[kl];
              v = (kl < ql) ? v : ((kl == ql) ? v + Dph : 0.f);
              o[i] = f2bs(v);
            }
            *(us4*)&Ms[w][(qm*16+lq)*40 + kn*16 + quad*4] = o;
          }
        }
        asm volatile("s_waitcnt lgkmcnt(0)" ::: "memory");
        // ydiag swapped: A=xsT(p rows), B=Ms(q rows) -> D[p=quad*4+i][q=lq]
        #pragma unroll
        for (int qm=0;qm<2;qm++){
          bf16x8 am = *(const bf16x8*)&Ms[w][(qm*16+lq)*40 + quad*8];
          #pragma unroll
          for (int pn=0;pn<8;pn++){
            bf16x8 bp = *(const bf16x8*)&xsT[(pn*16+lq)*72 + kb32 + quad*8];
            Yacc[half][qm][pn] = __builtin_amdgcn_mfma_f32_16x16x32_bf16(bp, am, Yacc[half][qm][pn], 0,0,0);
          }
        }
      }
    }
  }

  // ---- epilogue y: q = j*32+qm*16+lq (row), p = pn*16+quad*4 (4 cols)
  bf16* yrow = y + (size_t)z*CHUNK*D_INNER + h*HEADDIM;
  #pragma unroll
  for (int half=0; half<2; half++){
    const int j = half ? j1 : j0;
    #pragma unroll
    for (int qm=0;qm<2;qm++){
      int q = j*32 + qm*16 + lq;
      #pragma unroll
      for (int pn=0;pn<8;pn++)
        store4(&yrow[(size_t)q*D_INNER + pn*16 + quad*4], Yacc[half][qm][pn]);
    }
  }
  // ---- epilogue states: p = w*32+mi*16+lq (row), n = ni*16+quad*4 (4 cols)
  float* so = states + (size_t)bid*HEADDIM*D_STATE;
  #pragma unroll
  for (int mi=0;mi<2;mi++){
    int pp = w*32 + mi*16 + lq;
    #pragma unroll
    for (int ni=0;ni<4;ni++)
      store4(&so[pp*D_STATE + ni*16 + quad*4], Sst[mi][ni]);
  }
}

// ---------------------------------------------------------------------------
// Inter-chunk scan: prevb[c] = bf16(carry); carry = carry*cd + states[c]
// ---------------------------------------------------------------------------
__global__ __launch_bounds__(256) void k_scan(
    const float* __restrict__ states, const float* __restrict__ cd_t,
    bf16* __restrict__ prevb){
  int b = blockIdx.x >> 4, h = blockIdx.x & 15;
  int pt = blockIdx.y;
  int tid = threadIdx.x;
  float carry[4] = {0.f,0.f,0.f,0.f};
  for (int c=0;c<NC;c++){
    size_t base = ((size_t)(b*256 + c*16 + h))*HEADDIM*D_STATE + (size_t)pt*1024;
    float cd = cd_t[(b*NHEADS+h)*NC + c];
    #pragma unroll
    for (int i=0;i<4;i++){
      size_t idx = base + (size_t)i*256 + tid;
      prevb[idx] = __float2bfloat16(carry[i]);
      carry[i] = carry[i]*cd + states[idx];
    }
  }
}

// ---------------------------------------------------------------------------
// y[q, h*128+p] += exp(acum[q]) * sum_n C[q,n]*prev[h][p,n]   (MFMA, swapped)
// ---------------------------------------------------------------------------
__global__ __launch_bounds__(256,2) void k_yoff(
    const bf16* __restrict__ xbc, const bf16* __restrict__ prevb,
    const float* __restrict__ acum_t, bf16* __restrict__ y){
  const int bid = blockIdx.x;
  const int h = bid & 15, c = (bid>>4)&15, b = bid>>8;
  const int z = b*NC + c;
  const int tid = threadIdx.x;
  const int w = tid >> 6, l = tid & 63;
  const int quad = l >> 4, lq = l & 15;
  const bf16* Crow = xbc + (size_t)z*CHUNK*CONV_DIM + D_INNER + D_STATE;
  const bf16* pv = prevb + (size_t)bid*HEADDIM*D_STATE;
  const float* acum = acum_t + ((size_t)(b*NHEADS+h))*LEN + c*CHUNK;
  const int qw = w*64;
  f32x4 acc[4][8] = {};   // [qm][pn]; lane: q=lq, p=quad*4+i
  #pragma unroll
  for (int s=0;s<2;s++){
    bf16x8 bp[8];
    #pragma unroll
    for (int pn=0;pn<8;pn++)
      bp[pn] = *(const bf16x8*)(pv + (pn*16+lq)*D_STATE + s*32 + quad*8);
    #pragma unroll
    for (int qm=0;qm<4;qm++){
      int row = qw + qm*16 + lq;
      float e = __expf(acum[row]);
      bf16x8 a = *(const bf16x8*)(Crow + (size_t)row*CONV_DIM + s*32 + quad*8);
      bf16x8 ae;
      #pragma unroll
      for (int j=0;j<8;j++) ae[j] = (__bf16)((float)a[j] * e);
      #pragma unroll
      for (int pn=0;pn<8;pn++)
        acc[qm][pn] = __builtin_amdgcn_mfma_f32_16x16x32_bf16(bp[pn], ae, acc[qm][pn], 0,0,0);
    }
  }
  bf16* yrow = y + (size_t)z*CHUNK*D_INNER + h*HEADDIM;
  #pragma unroll
  for (int qm=0;qm<4;qm++){
    int q = qw + qm*16 + lq;
    #pragma unroll
    for (int pn=0;pn<8;pn++){
      bf16* yp = &yrow[(size_t)q*D_INNER + pn*16 + quad*4];
      us4 old = *(const us4*)yp;
      us4 o;
      #pragma unroll
      for (int i=0;i<4;i++)
        o[i] = f2bs(__bfloat162float(__ushort_as_bfloat16(old[i])) + acc[qm][pn][i]);
      *(us4*)yp = o;
    }
  }
}

// ---------------------------------------------------------------------------
// y = y * silu(z); y = y * rsqrt(mean(y^2)+eps) * norm_w   (in place, bf16)
// ---------------------------------------------------------------------------
__global__ __launch_bounds__(256) void k_gatenorm(
    const bf16* __restrict__ zxbct, const float* __restrict__ norm_w,
    bf16* __restrict__ y){
  int m = blockIdx.x;
  int e0 = threadIdx.x*8;
  bf16x8 zv = *(const bf16x8*)(zxbct + (size_t)m*ZPAD + e0);
  bf16x8 yv = *(const bf16x8*)(y + (size_t)m*D_INNER + e0);
  float4 nw0 = *(const float4*)(norm_w + e0);
  float4 nw1 = *(const float4*)(norm_w + e0 + 4);
  float v[8]; float ss = 0.f;
  #pragma unroll
  for (int j=0;j<8;j++){
    float val = (float)yv[j] * fsilu((float)zv[j]);
    v[j] = val; ss += val*val;
  }
  #pragma unroll
  for (int off=32; off>0; off>>=1) ss += __shfl_down(ss, off, 64);
  __shared__ float red[4];
  if ((threadIdx.x & 63) == 0) red[threadIdx.x >> 6] = ss;
  __syncthreads();
  float tot = red[0]+red[1]+red[2]+red[3];
  float r = rsqrtf(tot * (1.f/D_INNER) + 1e-5f);
  float nw[8] = {nw0.x,nw0.y,nw0.z,nw0.w,nw1.x,nw1.y,nw1.z,nw1.w};
  bf16x8 o;
  #pragma unroll
  for (int j=0;j<8;j++) o[j] = (__bf16)(v[j] * r * nw[j]);
  *(bf16x8*)(y + (size_t)m*D_INNER + e0) = o;
}

extern "C" void kernel_launch(void* const* d_in, const int* in_sizes, int n_in,
                              void* d_out, int out_size, void* d_ws, size_t ws_size,
                              hipStream_t stream) {
  const float* u         = (const float*)d_in[0];
  const float* in_proj_w = (const float*)d_in[1];
  const float* conv_w    = (const float*)d_in[2];
  const float* conv_b    = (const float*)d_in[3];
  const float* dt_bias   = (const float*)d_in[4];
  const float* A_log     = (const float*)d_in[5];
  const float* Dp        = (const float*)d_in[6];
  const float* norm_w    = (const float*)d_in[7];
  const float* out_proj_w= (const float*)d_in[8];
  float* out = (float*)d_out;

  char* p = (char*)d_ws;
  auto alloc = [&](size_t bytes){ char* r = p; p += (bytes + 255) & ~size_t(255); return r; };
  bf16*  zxbct = (bf16*) alloc((size_t)MROWS*ZPAD*2);                    //  71.3 MB
  bf16*  xbc   = (bf16*) alloc((size_t)MROWS*CONV_DIM*2);                //  35.7 MB
  bf16*  y     = (bf16*) alloc((size_t)MROWS*D_INNER*2);                 //  33.6 MB
  bf16*  ub    = (bf16*) alloc((size_t)MROWS*D_MODEL*2);                 //  16.8 MB (alias: states)
  bf16*  Wb_in = (bf16*) alloc((size_t)ZPAD*D_MODEL*2);                  //   8.9 MB (alias: prevb)
  bf16*  Wb_out= (bf16*) alloc((size_t)D_MODEL*D_INNER*2);               //   4.2 MB
  float* dt_t  = (float*)alloc((size_t)NB*NHEADS*LEN*4);                 //   0.5 MB
  float* acum_t= (float*)alloc((size_t)NB*NHEADS*LEN*4);                 //   0.5 MB
  float* cd_t  = (float*)alloc((size_t)NB*NHEADS*NC*4);                  //   tiny
  float* states= (float*)ub;     // 16.8 MB, live after in_proj GEMM
  bf16*  prevb = (bf16*)Wb_in;   //  8.4 MB, live after in_proj GEMM
  // total ~171.5 MB

  dim3 blk(256);
  k_tobf16<<<dim3((MROWS*D_MODEL+255)/256), blk, 0, stream>>>(u, ub, MROWS*D_MODEL);
  k_padW  <<<dim3((ZPAD*D_MODEL)/256), blk, 0, stream>>>(in_proj_w, Wb_in);
  k_tobf16<<<dim3((D_MODEL*D_INNER+255)/256), blk, 0, stream>>>(out_proj_w, Wb_out, D_MODEL*D_INNER);

  k_gemm_mfma<bf16><<<dim3(MROWS/128, ZPAD/128), blk, 0, stream>>>(
      ub, D_MODEL, Wb_in, D_MODEL, zxbct, ZPAD, D_MODEL);

  k_dt   <<<dim3(NB*NC*NHEADS), blk, 0, stream>>>(zxbct, dt_bias, A_log, dt_t, acum_t, cd_t);
  k_conv <<<dim3(CONV_DIM/64, MROWS/32), blk, 0, stream>>>(zxbct, conv_w, conv_b, xbc);
  k_fused<<<dim3(NB*NC*NHEADS), blk, 0, stream>>>(xbc, acum_t, dt_t, Dp, y, states);
  k_scan <<<dim3(NB*NHEADS, 8), blk, 0, stream>>>(states, cd_t, prevb);
  k_yoff <<<dim3(NB*NC*NHEADS), blk, 0, stream>>>(xbc, prevb, acum_t, y);
  k_gatenorm<<<dim3(MROWS), blk, 0, stream>>>(zxbct, norm_w, y);

  k_gemm_mfma<float><<<dim3(MROWS/128, D_MODEL/128), blk, 0, stream>>>(
      y, D_INNER, Wb_out, D_INNER, out, D_MODEL, D_INNER);
}

// Round 7
// 376.683 us; speedup vs baseline: 6.4052x; 1.1229x over previous
//
#include <hip/hip_runtime.h>
#include <hip/hip_bf16.h>
#include <cstdint>
#include <cstddef>

#define D_MODEL   1024
#define D_INNER   2048
#define D_STATE   64
#define HEADDIM   128
#define NHEADS    16
#define D_CONV    4
#define CHUNK     256
#define D_IN_PROJ 4240     // 2*D_INNER + 2*D_STATE + NHEADS
#define ZPAD      4352     // padded for MFMA tiles
#define CONV_DIM  2176     // D_INNER + 2*D_STATE
#define NB        2
#define LEN       4096
#define NC        16
#define MROWS     (NB*LEN) // 8192

typedef __hip_bfloat16 bf16;
typedef __bf16 bf16x8 __attribute__((ext_vector_type(8)));
typedef float  f32x4  __attribute__((ext_vector_type(4)));
typedef unsigned short us4 __attribute__((ext_vector_type(4)));

__device__ __forceinline__ float fsilu(float x){ return x / (1.f + __expf(-x)); }
__device__ __forceinline__ float toF(float x){ return x; }
__device__ __forceinline__ float toF(bf16 x){ return __bfloat162float(x); }
__device__ __forceinline__ void storeF(float* p, float v){ *p = v; }
__device__ __forceinline__ void storeF(bf16* p, float v){ *p = __float2bfloat16(v); }

__device__ __forceinline__ unsigned short f2bs(float v){
  return __bfloat16_as_ushort(__float2bfloat16(v));
}
__device__ __forceinline__ void store4(bf16* p, f32x4 v){
  us4 o; o[0]=f2bs(v[0]); o[1]=f2bs(v[1]); o[2]=f2bs(v[2]); o[3]=f2bs(v[3]);
  *(us4*)p = o;
}
__device__ __forceinline__ void store4(float* p, f32x4 v){
  *(f32x4*)p = v;
}

__device__ __forceinline__ void gload_lds16(const void* g, void* l){
  __builtin_amdgcn_global_load_lds(
     (const __attribute__((address_space(1))) unsigned int*)(uintptr_t)g,
     (__attribute__((address_space(3))) unsigned int*)(uintptr_t)l, 16, 0, 0);
}

// ---------------------------------------------------------------------------
// MFMA bf16 GEMM: C[m,n] = sum_k A[m,k]*B[n,k]
// 128x128 tile, BK=64 as two 32-wide LDS buffers (proven stride), one
// barrier pair per 64-K.  Operand-swapped epilogue (lane = 4 consecutive cols).
// ---------------------------------------------------------------------------
template<typename TC>
__global__ __launch_bounds__(256) void k_gemm_mfma(
    const bf16* __restrict__ A, int lda,
    const bf16* __restrict__ B, int ldb,
    TC* __restrict__ C, int ldc, int K)
{
  __shared__ __align__(16) bf16 As[2][128*32];
  __shared__ __align__(16) bf16 Bs[2][128*32];
  const int tid = threadIdx.x;
  const int w = tid >> 6, l = tid & 63;
  const int quad = l >> 4, lq = l & 15;
  const int m0 = blockIdx.x*128, n0 = blockIdx.y*128;
  const int wm = (w & 1)*64, wn = (w >> 1)*64;
  f32x4 acc[4][4] = {};
  const int sr = l >> 2;         // 0..15 row within 16-row block
  const int sc = (l & 3)*8;      // staging col (bf16 elems)

  for (int k0 = 0; k0 < K; k0 += 64) {
    #pragma unroll
    for (int half = 0; half < 2; half++){
      #pragma unroll
      for (int j = 0; j < 2; j++) {
        const int blk = w*2 + j;
        const int row = blk*16 + sr;
        gload_lds16(A + (size_t)(m0+row)*lda + k0 + half*32 + sc, (char*)As[half] + blk*1024);
        gload_lds16(B + (size_t)(n0+row)*ldb + k0 + half*32 + sc, (char*)Bs[half] + blk*1024);
      }
    }
    asm volatile("s_waitcnt vmcnt(0)" ::: "memory");
    __syncthreads();

    const int kq = quad*8;
    #pragma unroll
    for (int half = 0; half < 2; half++){
      bf16x8 af[4], bfr[4];
      #pragma unroll
      for (int t = 0; t < 4; t++){
        af[t]  = *(const bf16x8*)&As[half][(wm + lq + t*16)*32 + kq];
        bfr[t] = *(const bf16x8*)&Bs[half][(wn + lq + t*16)*32 + kq];
      }
      #pragma unroll
      for (int tm = 0; tm < 4; tm++)
        #pragma unroll
        for (int tn = 0; tn < 4; tn++)
          acc[tm][tn] = __builtin_amdgcn_mfma_f32_16x16x32_bf16(bfr[tn], af[tm], acc[tm][tn], 0,0,0);
    }
    __syncthreads();
  }

  #pragma unroll
  for (int tm = 0; tm < 4; tm++){
    int r = m0 + wm + tm*16 + lq;
    #pragma unroll
    for (int tn = 0; tn < 4; tn++){
      int cb = n0 + wn + tn*16 + quad*4;
      store4(&C[(size_t)r*ldc + cb], acc[tm][tn]);
    }
  }
}

// ---------------------------------------------------------------------------
// One fused conversion kernel (float4-vectorized):
//  u -> ub ; in_proj_w -> Wb_in (padded rows 0) ; out_proj_w*norm_w -> Wb_out
// ---------------------------------------------------------------------------
#define NU4  (MROWS*D_MODEL/4)
#define NW14 (ZPAD*D_MODEL/4)
#define NW24 (D_MODEL*D_INNER/4)
__global__ __launch_bounds__(256) void k_convert(
    const float* __restrict__ u, const float* __restrict__ Win,
    const float* __restrict__ Wout, const float* __restrict__ norm_w,
    bf16* __restrict__ ub, bf16* __restrict__ Wb_in, bf16* __restrict__ Wb_out){
  int i4 = blockIdx.x*256 + threadIdx.x;
  if (i4 < NU4){
    float4 v = ((const float4*)u)[i4];
    us4 o = {f2bs(v.x), f2bs(v.y), f2bs(v.z), f2bs(v.w)};
    ((us4*)ub)[i4] = o;
  } else if (i4 < NU4 + NW14){
    int j = i4 - NU4;
    int r = j >> 8;                        // row = (j*4)>>10
    float4 v = make_float4(0.f,0.f,0.f,0.f);
    if (r < D_IN_PROJ) v = ((const float4*)Win)[j];
    us4 o = {f2bs(v.x), f2bs(v.y), f2bs(v.z), f2bs(v.w)};
    ((us4*)Wb_in)[j] = o;
  } else {
    int j = i4 - NU4 - NW14;
    float4 v = ((const float4*)Wout)[j];
    float4 nw = ((const float4*)norm_w)[j & 511];   // k4 = j % (2048/4)
    us4 o = {f2bs(v.x*nw.x), f2bs(v.y*nw.y), f2bs(v.z*nw.z), f2bs(v.w*nw.w)};
    ((us4*)Wb_out)[j] = o;
  }
}

// ---------------------------------------------------------------------------
// dt = softplus(dt_raw + dt_bias); a = dt*A; inclusive cumsum over chunk.
// ---------------------------------------------------------------------------
__global__ __launch_bounds__(256) void k_dt(
    const bf16* __restrict__ zxbct, const float* __restrict__ dt_bias,
    const float* __restrict__ A_log, float* __restrict__ dt_t,
    float* __restrict__ acum_t, float* __restrict__ cd_t){
  int bid = blockIdx.x;
  int h = bid & 15, c = (bid>>4)&15, b = bid>>8;
  int q = threadIdx.x;
  size_t m = (size_t)(b*NC + c)*CHUNK + q;
  float x = toF(zxbct[m*ZPAD + (D_INNER + CONV_DIM) + h]) + dt_bias[h];
  float dtv = (x > 20.f) ? x : log1pf(__expf(x));
  float Ah = -__expf(A_log[h]);
  float a = dtv * Ah;
  __shared__ float sb[CHUNK];
  sb[q] = a;
  __syncthreads();
  #pragma unroll
  for (int off=1; off<CHUNK; off<<=1){
    float t = (q >= off) ? sb[q-off] : 0.f;
    __syncthreads();
    sb[q] += t;
    __syncthreads();
  }
  float ac = sb[q];
  size_t o = ((size_t)(b*NHEADS+h))*LEN + c*CHUNK + q;
  dt_t[o]   = dtv;
  acum_t[o] = ac;
  if (q == CHUNK-1) cd_t[(b*NHEADS+h)*NC + c] = __expf(ac);
}

// ---------------------------------------------------------------------------
// Depthwise causal conv (4 taps) + SiLU, LDS-staged.
// ---------------------------------------------------------------------------
__global__ __launch_bounds__(256) void k_conv(
    const bf16* __restrict__ zxbct, const float* __restrict__ conv_w,
    const float* __restrict__ conv_b, bf16* __restrict__ xbc){
  __shared__ __align__(16) __bf16 xs[35*64];
  __shared__ __align__(16) float  ws[64*4];
  __shared__ float bs[64];
  const int tid = threadIdx.x;
  const int cq = tid & 7;
  const int tm = tid >> 3;
  const int c0 = blockIdx.x*64;
  const int m0 = blockIdx.y*32;
  {
    int g = m0 - 3 + tm; if (g < 0) g = 0;
    *(bf16x8*)&xs[tm*64 + cq*8] =
        *(const bf16x8*)(zxbct + (size_t)g*ZPAD + D_INNER + c0 + cq*8);
    if (tid < 24){
      int r2 = 32 + (tid >> 3);
      int g2 = m0 - 3 + r2;
      *(bf16x8*)&xs[r2*64 + cq*8] =
          *(const bf16x8*)(zxbct + (size_t)g2*ZPAD + D_INNER + c0 + cq*8);
    }
  }
  if (tid < 64)      *(float4*)&ws[tid*4] = *(const float4*)(conv_w + (size_t)(c0+tid)*4);
  else if (tid < 128) bs[tid-64] = conv_b[c0 + tid - 64];
  __syncthreads();

  const int m = m0 + tm;
  const int l = m & (LEN-1);
  float acc[8];
  #pragma unroll
  for (int j=0;j<8;j++) acc[j] = bs[cq*8+j];
  #pragma unroll
  for (int w=0; w<D_CONV; w++){
    if (l - (D_CONV-1) + w >= 0){
      bf16x8 v = *(const bf16x8*)&xs[(tm+w)*64 + cq*8];
      #pragma unroll
      for (int j=0;j<8;j++) acc[j] += (float)v[j] * ws[(cq*8+j)*4 + w];
    }
  }
  bf16x8 o;
  #pragma unroll
  for (int j=0;j<8;j++) o[j] = (__bf16)fsilu(acc[j]);
  *(bf16x8*)(xbc + (size_t)m*CONV_DIM + c0 + cq*8) = o;
}

// ---------------------------------------------------------------------------
// FUSED per (b,c,h): scores -> coef+mask+Dp -> y_diag, plus chunk states.
// Balanced causal split: wave w owns q half-tiles j=w and j=7-w.
// ---------------------------------------------------------------------------
__global__ __launch_bounds__(256,2) void k_fused(
    const bf16* __restrict__ xbc, const float* __restrict__ acum_t,
    const float* __restrict__ dt_t, const float* __restrict__ Dp,
    bf16* __restrict__ y, float* __restrict__ states)
{
  const int bid = blockIdx.x;
  const int h = bid & 15, c = (bid>>4)&15, b = bid>>8;
  const int z = b*NC + c;
  const int tid = threadIdx.x;
  const int w = tid >> 6, l = tid & 63;
  const int quad = l >> 4, lq = l & 15;

  __shared__ __align__(16) __bf16 xsT[128*72];    // [p][k64]
  __shared__ __align__(16) __bf16 bts[64*72];     // [n][k64], w-scaled
  __shared__ __align__(16) __bf16 Ms[4][32*40];   // per-wave coef [q32][k32]
  __shared__ float acs[CHUNK], dts[CHUNK];

  const float* acum = acum_t + ((size_t)(b*NHEADS+h))*LEN + c*CHUNK;
  const float* dtc  = dt_t   + ((size_t)(b*NHEADS+h))*LEN + c*CHUNK;
  const float alast = acum[CHUNK-1];
  acs[tid] = acum[tid];
  dts[tid] = dtc[tid];

  const bf16* xrow = xbc + (size_t)z*CHUNK*CONV_DIM + h*HEADDIM;
  const bf16* Brow = xbc + (size_t)z*CHUNK*CONV_DIM + D_INNER;
  const bf16* Crow = xbc + (size_t)z*CHUNK*CONV_DIM + D_INNER + D_STATE;
  const float Dph = Dp[h];
  const int j0 = w, j1 = 7 - w;

  f32x4 Yacc[2][2][8] = {};   // [half][qm][pn]; lane: q=lq, p=quad*4+i
  f32x4 Sst[2][4]  = {};      // [mi][ni]; lane: p=lq, n=quad*4+i

  for (int t = 0; t < 4; t++){
    const int k0 = t*64;
    __syncthreads();
    {
      const bf16* xr = xrow + (size_t)(k0+l)*CONV_DIM;
      #pragma unroll
      for (int pass=0; pass<4; pass++){
        int pb = w*8 + pass*32;
        bf16x8 v = *(const bf16x8*)(xr + pb);
        #pragma unroll
        for (int j=0;j<8;j++) xsT[(pb+j)*72 + l] = v[j];
      }
      float wl = dts[k0+l] * __expf(alast - acs[k0+l]);
      const bf16* br = Brow + (size_t)(k0+l)*CONV_DIM;
      #pragma unroll
      for (int pass=0; pass<2; pass++){
        int nb = w*8 + pass*32;
        bf16x8 v = *(const bf16x8*)(br + nb);
        #pragma unroll
        for (int j=0;j<8;j++) bts[(nb+j)*72 + l] = (__bf16)((float)v[j] * wl);
      }
    }
    __syncthreads();

    // ---- states
    #pragma unroll
    for (int s=0;s<2;s++){
      bf16x8 a2[2];
      #pragma unroll
      for (int mi=0;mi<2;mi++)
        a2[mi] = *(const bf16x8*)&xsT[(w*32 + mi*16 + lq)*72 + s*32 + quad*8];
      #pragma unroll
      for (int ni=0;ni<4;ni++){
        bf16x8 bb = *(const bf16x8*)&bts[(ni*16+lq)*72 + s*32 + quad*8];
        #pragma unroll
        for (int mi=0;mi<2;mi++)
          Sst[mi][ni] = __builtin_amdgcn_mfma_f32_16x16x32_bf16(bb, a2[mi], Sst[mi][ni], 0,0,0);
      }
    }

    // ---- causal units
    #pragma unroll
    for (int half=0; half<2; half++){
      const int j = half ? j1 : j0;
      if (2*t > j) continue;
      const int qbase = j*32;
      bf16x8 cf[2][2];   // [s][qm] — q-dependent only, hoisted
      #pragma unroll
      for (int s=0;s<2;s++)
        #pragma unroll
        for (int qm=0;qm<2;qm++)
          cf[s][qm] = *(const bf16x8*)(Crow + (size_t)(qbase+qm*16+lq)*CONV_DIM + s*32 + quad*8);
      #pragma unroll
      for (int kk=0; kk<2; kk++){
        const int kh = 2*t + kk;
        if (kh > j) continue;
        const int kb32  = kk*32;
        const int kbase = kh*32;
        f32x4 Sacc[2][2] = {};  // [kn][qm]
        #pragma unroll
        for (int s=0;s<2;s++){
          bf16x8 bfk[2];
          #pragma unroll
          for (int kn=0;kn<2;kn++)
            bfk[kn] = *(const bf16x8*)(Brow + (size_t)(kbase+kn*16+lq)*CONV_DIM + s*32 + quad*8);
          #pragma unroll
          for (int kn=0;kn<2;kn++)
            #pragma unroll
            for (int qm=0;qm<2;qm++)
              Sacc[kn][qm] = __builtin_amdgcn_mfma_f32_16x16x32_bf16(bfk[kn], cf[s][qm], Sacc[kn][qm], 0,0,0);
        }
        #pragma unroll
        for (int qm=0;qm<2;qm++){
          int ql = qbase + qm*16 + lq;
          float aq = acs[ql];
          #pragma unroll
          for (int kn=0;kn<2;kn++){
            us4 o;
            #pragma unroll
            for (int i=0;i<4;i++){
              int kl = kbase + kn*16 + quad*4 + i;
              float v = Sacc[kn][qm][i] * __expf(aq - acs[kl]) * dts[kl];
              v = (kl < ql) ? v : ((kl == ql) ? v + Dph : 0.f);
              o[i] = f2bs(v);
            }
            *(us4*)&Ms[w][(qm*16+lq)*40 + kn*16 + quad*4] = o;
          }
        }
        asm volatile("s_waitcnt lgkmcnt(0)" ::: "memory");
        #pragma unroll
        for (int qm=0;qm<2;qm++){
          bf16x8 am = *(const bf16x8*)&Ms[w][(qm*16+lq)*40 + quad*8];
          #pragma unroll
          for (int pn=0;pn<8;pn++){
            bf16x8 bp = *(const bf16x8*)&xsT[(pn*16+lq)*72 + kb32 + quad*8];
            Yacc[half][qm][pn] = __builtin_amdgcn_mfma_f32_16x16x32_bf16(bp, am, Yacc[half][qm][pn], 0,0,0);
          }
        }
      }
    }
  }

  bf16* yrow = y + (size_t)z*CHUNK*D_INNER + h*HEADDIM;
  #pragma unroll
  for (int half=0; half<2; half++){
    const int j = half ? j1 : j0;
    #pragma unroll
    for (int qm=0;qm<2;qm++){
      int q = j*32 + qm*16 + lq;
      #pragma unroll
      for (int pn=0;pn<8;pn++)
        store4(&yrow[(size_t)q*D_INNER + pn*16 + quad*4], Yacc[half][qm][pn]);
    }
  }
  float* so = states + (size_t)bid*HEADDIM*D_STATE;
  #pragma unroll
  for (int mi=0;mi<2;mi++){
    int pp = w*32 + mi*16 + lq;
    #pragma unroll
    for (int ni=0;ni<4;ni++)
      store4(&so[pp*D_STATE + ni*16 + quad*4], Sst[mi][ni]);
  }
}

// ---------------------------------------------------------------------------
// Inter-chunk scan: prevb[c] = bf16(carry); carry = carry*cd + states[c]
// ---------------------------------------------------------------------------
__global__ __launch_bounds__(256) void k_scan(
    const float* __restrict__ states, const float* __restrict__ cd_t,
    bf16* __restrict__ prevb){
  int b = blockIdx.x >> 4, h = blockIdx.x & 15;
  int pt = blockIdx.y;
  int tid = threadIdx.x;
  float carry[4] = {0.f,0.f,0.f,0.f};
  for (int c=0;c<NC;c++){
    size_t base = ((size_t)(b*256 + c*16 + h))*HEADDIM*D_STATE + (size_t)pt*1024;
    float cd = cd_t[(b*NHEADS+h)*NC + c];
    #pragma unroll
    for (int i=0;i<4;i++){
      size_t idx = base + (size_t)i*256 + tid;
      prevb[idx] = __float2bfloat16(carry[i]);
      carry[i] = carry[i]*cd + states[idx];
    }
  }
}

// ---------------------------------------------------------------------------
// y[q, h*128+p] += exp(acum[q]) * sum_n C[q,n]*prev[h][p,n]   (MFMA, swapped)
// ---------------------------------------------------------------------------
__global__ __launch_bounds__(256,2) void k_yoff(
    const bf16* __restrict__ xbc, const bf16* __restrict__ prevb,
    const float* __restrict__ acum_t, bf16* __restrict__ y){
  const int bid = blockIdx.x;
  const int h = bid & 15, c = (bid>>4)&15, b = bid>>8;
  const int z = b*NC + c;
  const int tid = threadIdx.x;
  const int w = tid >> 6, l = tid & 63;
  const int quad = l >> 4, lq = l & 15;
  const bf16* Crow = xbc + (size_t)z*CHUNK*CONV_DIM + D_INNER + D_STATE;
  const bf16* pv = prevb + (size_t)bid*HEADDIM*D_STATE;
  const float* acum = acum_t + ((size_t)(b*NHEADS+h))*LEN + c*CHUNK;
  const int qw = w*64;
  f32x4 acc[4][8] = {};
  #pragma unroll
  for (int s=0;s<2;s++){
    bf16x8 bp[8];
    #pragma unroll
    for (int pn=0;pn<8;pn++)
      bp[pn] = *(const bf16x8*)(pv + (pn*16+lq)*D_STATE + s*32 + quad*8);
    #pragma unroll
    for (int qm=0;qm<4;qm++){
      int row = qw + qm*16 + lq;
      float e = __expf(acum[row]);
      bf16x8 a = *(const bf16x8*)(Crow + (size_t)row*CONV_DIM + s*32 + quad*8);
      bf16x8 ae;
      #pragma unroll
      for (int j=0;j<8;j++) ae[j] = (__bf16)((float)a[j] * e);
      #pragma unroll
      for (int pn=0;pn<8;pn++)
        acc[qm][pn] = __builtin_amdgcn_mfma_f32_16x16x32_bf16(bp[pn], ae, acc[qm][pn], 0,0,0);
    }
  }
  bf16* yrow = y + (size_t)z*CHUNK*D_INNER + h*HEADDIM;
  #pragma unroll
  for (int qm=0;qm<4;qm++){
    int q = qw + qm*16 + lq;
    #pragma unroll
    for (int pn=0;pn<8;pn++){
      bf16* yp = &yrow[(size_t)q*D_INNER + pn*16 + quad*4];
      us4 old = *(const us4*)yp;
      us4 o;
      #pragma unroll
      for (int i=0;i<4;i++)
        o[i] = f2bs(__bfloat162float(__ushort_as_bfloat16(old[i])) + acc[qm][pn][i]);
      *(us4*)yp = o;
    }
  }
}

// ---------------------------------------------------------------------------
// y = y * silu(z) * rsqrt(mean(...)+eps)   (norm_w folded into Wb_out)
// ---------------------------------------------------------------------------
__global__ __launch_bounds__(256) void k_gatenorm(
    const bf16* __restrict__ zxbct, bf16* __restrict__ y){
  int m = blockIdx.x;
  int e0 = threadIdx.x*8;
  bf16x8 zv = *(const bf16x8*)(zxbct + (size_t)m*ZPAD + e0);
  bf16x8 yv = *(const bf16x8*)(y + (size_t)m*D_INNER + e0);
  float v[8]; float ss = 0.f;
  #pragma unroll
  for (int j=0;j<8;j++){
    float val = (float)yv[j] * fsilu((float)zv[j]);
    v[j] = val; ss += val*val;
  }
  #pragma unroll
  for (int off=32; off>0; off>>=1) ss += __shfl_down(ss, off, 64);
  __shared__ float red[4];
  if ((threadIdx.x & 63) == 0) red[threadIdx.x >> 6] = ss;
  __syncthreads();
  float tot = red[0]+red[1]+red[2]+red[3];
  float r = rsqrtf(tot * (1.f/D_INNER) + 1e-5f);
  bf16x8 o;
  #pragma unroll
  for (int j=0;j<8;j++) o[j] = (__bf16)(v[j] * r);
  *(bf16x8*)(y + (size_t)m*D_INNER + e0) = o;
}

extern "C" void kernel_launch(void* const* d_in, const int* in_sizes, int n_in,
                              void* d_out, int out_size, void* d_ws, size_t ws_size,
                              hipStream_t stream) {
  const float* u         = (const float*)d_in[0];
  const float* in_proj_w = (const float*)d_in[1];
  const float* conv_w    = (const float*)d_in[2];
  const float* conv_b    = (const float*)d_in[3];
  const float* dt_bias   = (const float*)d_in[4];
  const float* A_log     = (const float*)d_in[5];
  const float* Dp        = (const float*)d_in[6];
  const float* norm_w    = (const float*)d_in[7];
  const float* out_proj_w= (const float*)d_in[8];
  float* out = (float*)d_out;

  char* p = (char*)d_ws;
  auto alloc = [&](size_t bytes){ char* r = p; p += (bytes + 255) & ~size_t(255); return r; };
  bf16*  zxbct = (bf16*) alloc((size_t)MROWS*ZPAD*2);                    //  71.3 MB
  bf16*  xbc   = (bf16*) alloc((size_t)MROWS*CONV_DIM*2);                //  35.7 MB
  bf16*  y     = (bf16*) alloc((size_t)MROWS*D_INNER*2);                 //  33.6 MB
  bf16*  ub    = (bf16*) alloc((size_t)MROWS*D_MODEL*2);                 //  16.8 MB (alias: states)
  bf16*  Wb_in = (bf16*) alloc((size_t)ZPAD*D_MODEL*2);                  //   8.9 MB (alias: prevb)
  bf16*  Wb_out= (bf16*) alloc((size_t)D_MODEL*D_INNER*2);               //   4.2 MB
  float* dt_t  = (float*)alloc((size_t)NB*NHEADS*LEN*4);                 //   0.5 MB
  float* acum_t= (float*)alloc((size_t)NB*NHEADS*LEN*4);                 //   0.5 MB
  float* cd_t  = (float*)alloc((size_t)NB*NHEADS*NC*4);                  //   tiny
  float* states= (float*)ub;     // 16.8 MB, live after in_proj GEMM
  bf16*  prevb = (bf16*)Wb_in;   //  8.4 MB, live after in_proj GEMM
  // total ~171.5 MB

  dim3 blk(256);
  k_convert<<<dim3((NU4+NW14+NW24)/256), blk, 0, stream>>>(
      u, in_proj_w, out_proj_w, norm_w, ub, Wb_in, Wb_out);

  k_gemm_mfma<bf16><<<dim3(MROWS/128, ZPAD/128), blk, 0, stream>>>(
      ub, D_MODEL, Wb_in, D_MODEL, zxbct, ZPAD, D_MODEL);

  k_dt   <<<dim3(NB*NC*NHEADS), blk, 0, stream>>>(zxbct, dt_bias, A_log, dt_t, acum_t, cd_t);
  k_conv <<<dim3(CONV_DIM/64, MROWS/32), blk, 0, stream>>>(zxbct, conv_w, conv_b, xbc);
  k_fused<<<dim3(NB*NC*NHEADS), blk, 0, stream>>>(xbc, acum_t, dt_t, Dp, y, states);
  k_scan <<<dim3(NB*NHEADS, 8), blk, 0, stream>>>(states, cd_t, prevb);
  k_yoff <<<dim3(NB*NC*NHEADS), blk, 0, stream>>>(xbc, prevb, acum_t, y);
  k_gatenorm<<<dim3(MROWS), blk, 0, stream>>>(zxbct, y);

  k_gemm_mfma<float><<<dim3(MROWS/128, D_MODEL/128), blk, 0, stream>>>(
      y, D_INNER, Wb_out, D_INNER, out, D_MODEL, D_INNER);
}

// Round 8
// 372.939 us; speedup vs baseline: 6.4695x; 1.0100x over previous
//
#include <hip/hip_runtime.h>
#include <hip/hip_bf16.h>
#include <cstdint>
#include <cstddef>

#define D_MODEL   1024
#define D_INNER   2048
#define D_STATE   64
#define HEADDIM   128
#define NHEADS    16
#define D_CONV    4
#define CHUNK     256
#define D_IN_PROJ 4240     // 2*D_INNER + 2*D_STATE + NHEADS
#define ZPAD      4352     // padded for MFMA tiles
#define CONV_DIM  2176     // D_INNER + 2*D_STATE
#define NB        2
#define LEN       4096
#define NC        16
#define MROWS     (NB*LEN) // 8192

typedef __hip_bfloat16 bf16;
typedef __bf16 bf16x8 __attribute__((ext_vector_type(8)));
typedef float  f32x4  __attribute__((ext_vector_type(4)));
typedef unsigned short us4 __attribute__((ext_vector_type(4)));

__device__ __forceinline__ float fsilu(float x){ return x / (1.f + __expf(-x)); }
__device__ __forceinline__ float toF(float x){ return x; }
__device__ __forceinline__ float toF(bf16 x){ return __bfloat162float(x); }
__device__ __forceinline__ void storeF(float* p, float v){ *p = v; }
__device__ __forceinline__ void storeF(bf16* p, float v){ *p = __float2bfloat16(v); }

__device__ __forceinline__ unsigned short f2bs(float v){
  return __bfloat16_as_ushort(__float2bfloat16(v));
}
__device__ __forceinline__ void store4(bf16* p, f32x4 v){
  us4 o; o[0]=f2bs(v[0]); o[1]=f2bs(v[1]); o[2]=f2bs(v[2]); o[3]=f2bs(v[3]);
  *(us4*)p = o;
}
__device__ __forceinline__ void store4(float* p, f32x4 v){
  *(f32x4*)p = v;
}

__device__ __forceinline__ void gload_lds16(const void* g, void* l){
  __builtin_amdgcn_global_load_lds(
     (const __attribute__((address_space(1))) unsigned int*)(uintptr_t)g,
     (__attribute__((address_space(3))) unsigned int*)(uintptr_t)l, 16, 0, 0);
}

// ---------------------------------------------------------------------------
// MFMA bf16 GEMM: C[m,n] = sum_k A[m,k]*B[n,k]
// 128x128 tile, BK=64 as two 32-wide LDS buffers, operand-swapped epilogue.
// ---------------------------------------------------------------------------
template<typename TC>
__global__ __launch_bounds__(256) void k_gemm_mfma(
    const bf16* __restrict__ A, int lda,
    const bf16* __restrict__ B, int ldb,
    TC* __restrict__ C, int ldc, int K)
{
  __shared__ __align__(16) bf16 As[2][128*32];
  __shared__ __align__(16) bf16 Bs[2][128*32];
  const int tid = threadIdx.x;
  const int w = tid >> 6, l = tid & 63;
  const int quad = l >> 4, lq = l & 15;
  const int m0 = blockIdx.x*128, n0 = blockIdx.y*128;
  const int wm = (w & 1)*64, wn = (w >> 1)*64;
  f32x4 acc[4][4] = {};
  const int sr = l >> 2;
  const int sc = (l & 3)*8;

  for (int k0 = 0; k0 < K; k0 += 64) {
    #pragma unroll
    for (int half = 0; half < 2; half++){
      #pragma unroll
      for (int j = 0; j < 2; j++) {
        const int blk = w*2 + j;
        const int row = blk*16 + sr;
        gload_lds16(A + (size_t)(m0+row)*lda + k0 + half*32 + sc, (char*)As[half] + blk*1024);
        gload_lds16(B + (size_t)(n0+row)*ldb + k0 + half*32 + sc, (char*)Bs[half] + blk*1024);
      }
    }
    asm volatile("s_waitcnt vmcnt(0)" ::: "memory");
    __syncthreads();

    const int kq = quad*8;
    #pragma unroll
    for (int half = 0; half < 2; half++){
      bf16x8 af[4], bfr[4];
      #pragma unroll
      for (int t = 0; t < 4; t++){
        af[t]  = *(const bf16x8*)&As[half][(wm + lq + t*16)*32 + kq];
        bfr[t] = *(const bf16x8*)&Bs[half][(wn + lq + t*16)*32 + kq];
      }
      #pragma unroll
      for (int tm = 0; tm < 4; tm++)
        #pragma unroll
        for (int tn = 0; tn < 4; tn++)
          acc[tm][tn] = __builtin_amdgcn_mfma_f32_16x16x32_bf16(bfr[tn], af[tm], acc[tm][tn], 0,0,0);
    }
    __syncthreads();
  }

  #pragma unroll
  for (int tm = 0; tm < 4; tm++){
    int r = m0 + wm + tm*16 + lq;
    #pragma unroll
    for (int tn = 0; tn < 4; tn++){
      int cb = n0 + wn + tn*16 + quad*4;
      store4(&C[(size_t)r*ldc + cb], acc[tm][tn]);
    }
  }
}

// ---------------------------------------------------------------------------
// Fused conversions: u->ub ; in_proj_w->Wb_in (padded) ; out_proj_w*norm_w->Wb_out
// ---------------------------------------------------------------------------
#define NU4  (MROWS*D_MODEL/4)
#define NW14 (ZPAD*D_MODEL/4)
#define NW24 (D_MODEL*D_INNER/4)
__global__ __launch_bounds__(256) void k_convert(
    const float* __restrict__ u, const float* __restrict__ Win,
    const float* __restrict__ Wout, const float* __restrict__ norm_w,
    bf16* __restrict__ ub, bf16* __restrict__ Wb_in, bf16* __restrict__ Wb_out){
  int i4 = blockIdx.x*256 + threadIdx.x;
  if (i4 < NU4){
    float4 v = ((const float4*)u)[i4];
    us4 o = {f2bs(v.x), f2bs(v.y), f2bs(v.z), f2bs(v.w)};
    ((us4*)ub)[i4] = o;
  } else if (i4 < NU4 + NW14){
    int j = i4 - NU4;
    int r = j >> 8;
    float4 v = make_float4(0.f,0.f,0.f,0.f);
    if (r < D_IN_PROJ) v = ((const float4*)Win)[j];
    us4 o = {f2bs(v.x), f2bs(v.y), f2bs(v.z), f2bs(v.w)};
    ((us4*)Wb_in)[j] = o;
  } else {
    int j = i4 - NU4 - NW14;
    float4 v = ((const float4*)Wout)[j];
    float4 nw = ((const float4*)norm_w)[j & 511];
    us4 o = {f2bs(v.x*nw.x), f2bs(v.y*nw.y), f2bs(v.z*nw.z), f2bs(v.w*nw.w)};
    ((us4*)Wb_out)[j] = o;
  }
}

// ---------------------------------------------------------------------------
// dt = softplus(dt_raw + dt_bias); a = dt*A; inclusive cumsum over chunk.
// ---------------------------------------------------------------------------
__global__ __launch_bounds__(256) void k_dt(
    const bf16* __restrict__ zxbct, const float* __restrict__ dt_bias,
    const float* __restrict__ A_log, float* __restrict__ dt_t,
    float* __restrict__ acum_t, float* __restrict__ cd_t){
  int bid = blockIdx.x;
  int h = bid & 15, c = (bid>>4)&15, b = bid>>8;
  int q = threadIdx.x;
  size_t m = (size_t)(b*NC + c)*CHUNK + q;
  float x = toF(zxbct[m*ZPAD + (D_INNER + CONV_DIM) + h]) + dt_bias[h];
  float dtv = (x > 20.f) ? x : log1pf(__expf(x));
  float Ah = -__expf(A_log[h]);
  float a = dtv * Ah;
  __shared__ float sb[CHUNK];
  sb[q] = a;
  __syncthreads();
  #pragma unroll
  for (int off=1; off<CHUNK; off<<=1){
    float t = (q >= off) ? sb[q-off] : 0.f;
    __syncthreads();
    sb[q] += t;
    __syncthreads();
  }
  float ac = sb[q];
  size_t o = ((size_t)(b*NHEADS+h))*LEN + c*CHUNK + q;
  dt_t[o]   = dtv;
  acum_t[o] = ac;
  if (q == CHUNK-1) cd_t[(b*NHEADS+h)*NC + c] = __expf(ac);
}

// ---------------------------------------------------------------------------
// Depthwise causal conv (4 taps) + SiLU, LDS-staged.  64 ch x 64 rows/block.
// ---------------------------------------------------------------------------
__global__ __launch_bounds__(256) void k_conv(
    const bf16* __restrict__ zxbct, const float* __restrict__ conv_w,
    const float* __restrict__ conv_b, bf16* __restrict__ xbc){
  __shared__ __align__(16) __bf16 xs[67*64];
  __shared__ __align__(16) float  ws[64*4];
  __shared__ float bs[64];
  const int tid = threadIdx.x;
  const int cq = tid & 7;
  const int tm = tid >> 3;          // 0..31
  const int c0 = blockIdx.x*64;
  const int m0 = blockIdx.y*64;
  {
    int g = m0 - 3 + tm; if (g < 0) g = 0;
    *(bf16x8*)&xs[tm*64 + cq*8] =
        *(const bf16x8*)(zxbct + (size_t)g*ZPAD + D_INNER + c0 + cq*8);
    int g2 = m0 - 3 + tm + 32;
    *(bf16x8*)&xs[(tm+32)*64 + cq*8] =
        *(const bf16x8*)(zxbct + (size_t)g2*ZPAD + D_INNER + c0 + cq*8);
    if (tid < 24){
      int r3 = 64 + (tid >> 3);
      int g3 = m0 - 3 + r3;
      *(bf16x8*)&xs[r3*64 + cq*8] =
          *(const bf16x8*)(zxbct + (size_t)g3*ZPAD + D_INNER + c0 + cq*8);
    }
  }
  if (tid < 64)      *(float4*)&ws[tid*4] = *(const float4*)(conv_w + (size_t)(c0+tid)*4);
  else if (tid < 128) bs[tid-64] = conv_b[c0 + tid - 64];
  __syncthreads();

  #pragma unroll
  for (int rr=0; rr<2; rr++){
    const int r = tm + rr*32;
    const int m = m0 + r;
    const int l = m & (LEN-1);
    float acc[8];
    #pragma unroll
    for (int j=0;j<8;j++) acc[j] = bs[cq*8+j];
    #pragma unroll
    for (int w=0; w<D_CONV; w++){
      if (l - (D_CONV-1) + w >= 0){
        bf16x8 v = *(const bf16x8*)&xs[(r+w)*64 + cq*8];
        #pragma unroll
        for (int j=0;j<8;j++) acc[j] += (float)v[j] * ws[(cq*8+j)*4 + w];
      }
    }
    bf16x8 o;
    #pragma unroll
    for (int j=0;j<8;j++) o[j] = (__bf16)fsilu(acc[j]);
    *(bf16x8*)(xbc + (size_t)m*CONV_DIM + c0 + cq*8) = o;
  }
}

// ---------------------------------------------------------------------------
// k_states per (b,c,h): states[p,n] = sum_q dt[q]*exp(alast-acum[q])*x[q,p]*B[q,n]
// Double-buffered transposed staging, 1 barrier per k-tile.
// ---------------------------------------------------------------------------
__global__ __launch_bounds__(256,2) void k_states(
    const bf16* __restrict__ xbc, const float* __restrict__ acum_t,
    const float* __restrict__ dt_t, float* __restrict__ states)
{
  const int bid = blockIdx.x;
  const int h = bid & 15, c = (bid>>4)&15, b = bid>>8;
  const int z = b*NC + c;
  const int tid = threadIdx.x;
  const int w = tid >> 6, l = tid & 63;
  const int quad = l >> 4, lq = l & 15;

  __shared__ __align__(16) __bf16 xsT[2][128*72];
  __shared__ __align__(16) __bf16 bts[2][64*72];

  const float* acum = acum_t + ((size_t)(b*NHEADS+h))*LEN + c*CHUNK;
  const float* dtc  = dt_t   + ((size_t)(b*NHEADS+h))*LEN + c*CHUNK;
  const float alast = acum[CHUNK-1];
  const bf16* xrow = xbc + (size_t)z*CHUNK*CONV_DIM + h*HEADDIM;
  const bf16* Brow = xbc + (size_t)z*CHUNK*CONV_DIM + D_INNER;

  f32x4 Sst[2][4] = {};

  auto stage = [&](int t, int buf){
    const int k0 = t*64;
    const bf16* xr = xrow + (size_t)(k0+l)*CONV_DIM;
    #pragma unroll
    for (int pass=0; pass<4; pass++){
      int pb = w*8 + pass*32;
      bf16x8 v = *(const bf16x8*)(xr + pb);
      #pragma unroll
      for (int j=0;j<8;j++) xsT[buf][(pb+j)*72 + l] = v[j];
    }
    float wl = dtc[k0+l] * __expf(alast - acum[k0+l]);
    const bf16* br = Brow + (size_t)(k0+l)*CONV_DIM;
    #pragma unroll
    for (int pass=0; pass<2; pass++){
      int nb = w*8 + pass*32;
      bf16x8 v = *(const bf16x8*)(br + nb);
      #pragma unroll
      for (int j=0;j<8;j++) bts[buf][(nb+j)*72 + l] = (__bf16)((float)v[j] * wl);
    }
  };

  stage(0, 0);
  for (int t = 0; t < 4; t++){
    const int buf = t & 1;
    __syncthreads();
    if (t < 3) stage(t+1, buf^1);
    #pragma unroll
    for (int s=0;s<2;s++){
      bf16x8 a2[2];
      #pragma unroll
      for (int mi=0;mi<2;mi++)
        a2[mi] = *(const bf16x8*)&xsT[buf][(w*32 + mi*16 + lq)*72 + s*32 + quad*8];
      #pragma unroll
      for (int ni=0;ni<4;ni++){
        bf16x8 bb = *(const bf16x8*)&bts[buf][(ni*16+lq)*72 + s*32 + quad*8];
        #pragma unroll
        for (int mi=0;mi<2;mi++)
          Sst[mi][ni] = __builtin_amdgcn_mfma_f32_16x16x32_bf16(bb, a2[mi], Sst[mi][ni], 0,0,0);
      }
    }
  }

  float* so = states + (size_t)bid*HEADDIM*D_STATE;
  #pragma unroll
  for (int mi=0;mi<2;mi++){
    int pp = w*32 + mi*16 + lq;
    #pragma unroll
    for (int ni=0;ni<4;ni++)
      store4(&so[pp*D_STATE + ni*16 + quad*4], Sst[mi][ni]);
  }
}

// ---------------------------------------------------------------------------
// Inter-chunk scan: prevb[c] = bf16(carry); carry = carry*cd + states[c]
// ---------------------------------------------------------------------------
__global__ __launch_bounds__(256) void k_scan(
    const float* __restrict__ states, const float* __restrict__ cd_t,
    bf16* __restrict__ prevb){
  int b = blockIdx.x >> 4, h = blockIdx.x & 15;
  int pt = blockIdx.y;
  int tid = threadIdx.x;
  float carry[4] = {0.f,0.f,0.f,0.f};
  for (int c=0;c<NC;c++){
    size_t base = ((size_t)(b*256 + c*16 + h))*HEADDIM*D_STATE + (size_t)pt*1024;
    float cd = cd_t[(b*NHEADS+h)*NC + c];
    #pragma unroll
    for (int i=0;i<4;i++){
      size_t idx = base + (size_t)i*256 + tid;
      prevb[idx] = __float2bfloat16(carry[i]);
      carry[i] = carry[i]*cd + states[idx];
    }
  }
}

// ---------------------------------------------------------------------------
// FUSED per (b,c,h): y = y_off (from prevb) + y_diag (scores->coef->PV) + x*Dp.
// Single write of y.  Balanced causal split (wave w owns q half-tiles w, 7-w).
// Double-buffered x^T staging, 1 barrier per k-tile.
// ---------------------------------------------------------------------------
__global__ __launch_bounds__(256,2) void k_fused(
    const bf16* __restrict__ xbc, const float* __restrict__ acum_t,
    const float* __restrict__ dt_t, const float* __restrict__ Dp,
    const bf16* __restrict__ prevb, bf16* __restrict__ y)
{
  const int bid = blockIdx.x;
  const int h = bid & 15, c = (bid>>4)&15, b = bid>>8;
  const int z = b*NC + c;
  const int tid = threadIdx.x;
  const int w = tid >> 6, l = tid & 63;
  const int quad = l >> 4, lq = l & 15;

  __shared__ __align__(16) __bf16 xsT[2][128*72];   // [p][k64] double-buffered
  __shared__ __align__(16) __bf16 Ms[4][32*40];     // per-wave coef [q32][k32]
  __shared__ float acs[CHUNK], dts[CHUNK];

  const float* acum = acum_t + ((size_t)(b*NHEADS+h))*LEN + c*CHUNK;
  const float* dtc  = dt_t   + ((size_t)(b*NHEADS+h))*LEN + c*CHUNK;
  acs[tid] = acum[tid];
  dts[tid] = dtc[tid];

  const bf16* xrow = xbc + (size_t)z*CHUNK*CONV_DIM + h*HEADDIM;
  const bf16* Brow = xbc + (size_t)z*CHUNK*CONV_DIM + D_INNER;
  const bf16* Crow = xbc + (size_t)z*CHUNK*CONV_DIM + D_INNER + D_STATE;
  const bf16* pv   = prevb + (size_t)bid*HEADDIM*D_STATE;
  const float Dph = Dp[h];
  const int j0 = w, j1 = 7 - w;

  f32x4 Yacc[2][2][8] = {};   // [half][qm][pn]; lane: q=lq, p=quad*4+i

  auto stage = [&](int t, int buf){
    const bf16* xr = xrow + (size_t)(t*64+l)*CONV_DIM;
    #pragma unroll
    for (int pass=0; pass<4; pass++){
      int pb = w*8 + pass*32;
      bf16x8 v = *(const bf16x8*)(xr + pb);
      #pragma unroll
      for (int j=0;j<8;j++) xsT[buf][(pb+j)*72 + l] = v[j];
    }
  };

  stage(0, 0);
  __syncthreads();   // covers acs/dts too

  // ---- y_off: Yacc += mfma(prevb p-rows, exp(acum_q)*C q-rows)
  #pragma unroll
  for (int s=0;s<2;s++){
    bf16x8 bp[8];
    #pragma unroll
    for (int pn=0;pn<8;pn++)
      bp[pn] = *(const bf16x8*)(pv + (pn*16+lq)*D_STATE + s*32 + quad*8);
    #pragma unroll
    for (int half=0; half<2; half++){
      const int j = half ? j1 : j0;
      #pragma unroll
      for (int qm=0;qm<2;qm++){
        int row = j*32 + qm*16 + lq;
        float e = __expf(acs[row]);
        bf16x8 a = *(const bf16x8*)(Crow + (size_t)row*CONV_DIM + s*32 + quad*8);
        bf16x8 ae;
        #pragma unroll
        for (int jj=0;jj<8;jj++) ae[jj] = (__bf16)((float)a[jj] * e);
        #pragma unroll
        for (int pn=0;pn<8;pn++)
          Yacc[half][qm][pn] = __builtin_amdgcn_mfma_f32_16x16x32_bf16(bp[pn], ae, Yacc[half][qm][pn], 0,0,0);
      }
    }
  }

  for (int t = 0; t < 4; t++){
    const int buf = t & 1;
    if (t > 0) __syncthreads();
    if (t < 3) stage(t+1, buf^1);

    #pragma unroll
    for (int half=0; half<2; half++){
      const int j = half ? j1 : j0;
      if (2*t > j) continue;
      const int qbase = j*32;
      bf16x8 cf[2][2];   // [s][qm]
      #pragma unroll
      for (int s=0;s<2;s++)
        #pragma unroll
        for (int qm=0;qm<2;qm++)
          cf[s][qm] = *(const bf16x8*)(Crow + (size_t)(qbase+qm*16+lq)*CONV_DIM + s*32 + quad*8);
      #pragma unroll
      for (int kk=0; kk<2; kk++){
        const int kh = 2*t + kk;
        if (kh > j) continue;
        const int kb32  = kk*32;
        const int kbase = kh*32;
        f32x4 Sacc[2][2] = {};  // [kn][qm]
        #pragma unroll
        for (int s=0;s<2;s++){
          bf16x8 bfk[2];
          #pragma unroll
          for (int kn=0;kn<2;kn++)
            bfk[kn] = *(const bf16x8*)(Brow + (size_t)(kbase+kn*16+lq)*CONV_DIM + s*32 + quad*8);
          #pragma unroll
          for (int kn=0;kn<2;kn++)
            #pragma unroll
            for (int qm=0;qm<2;qm++)
              Sacc[kn][qm] = __builtin_amdgcn_mfma_f32_16x16x32_bf16(bfk[kn], cf[s][qm], Sacc[kn][qm], 0,0,0);
        }
        #pragma unroll
        for (int qm=0;qm<2;qm++){
          int ql = qbase + qm*16 + lq;
          float aq = acs[ql];
          #pragma unroll
          for (int kn=0;kn<2;kn++){
            us4 o;
            #pragma unroll
            for (int i=0;i<4;i++){
              int kl = kbase + kn*16 + quad*4 + i;
              float v = Sacc[kn][qm][i] * __expf(aq - acs[kl]) * dts[kl];
              v = (kl < ql) ? v : ((kl == ql) ? v + Dph : 0.f);
              o[i] = f2bs(v);
            }
            *(us4*)&Ms[w][(qm*16+lq)*40 + kn*16 + quad*4] = o;
          }
        }
        asm volatile("s_waitcnt lgkmcnt(0)" ::: "memory");
        #pragma unroll
        for (int qm=0;qm<2;qm++){
          bf16x8 am = *(const bf16x8*)&Ms[w][(qm*16+lq)*40 + quad*8];
          #pragma unroll
          for (int pn=0;pn<8;pn++){
            bf16x8 bp = *(const bf16x8*)&xsT[buf][(pn*16+lq)*72 + kb32 + quad*8];
            Yacc[half][qm][pn] = __builtin_amdgcn_mfma_f32_16x16x32_bf16(bp, am, Yacc[half][qm][pn], 0,0,0);
          }
        }
      }
    }
  }

  bf16* yrow = y + (size_t)z*CHUNK*D_INNER + h*HEADDIM;
  #pragma unroll
  for (int half=0; half<2; half++){
    const int j = half ? j1 : j0;
    #pragma unroll
    for (int qm=0;qm<2;qm++){
      int q = j*32 + qm*16 + lq;
      #pragma unroll
      for (int pn=0;pn<8;pn++)
        store4(&yrow[(size_t)q*D_INNER + pn*16 + quad*4], Yacc[half][qm][pn]);
    }
  }
}

// ---------------------------------------------------------------------------
// y = y * silu(z) * rsqrt(mean(...)+eps)   (norm_w folded into Wb_out)
// ---------------------------------------------------------------------------
__global__ __launch_bounds__(256) void k_gatenorm(
    const bf16* __restrict__ zxbct, bf16* __restrict__ y){
  int m = blockIdx.x;
  int e0 = threadIdx.x*8;
  bf16x8 zv = *(const bf16x8*)(zxbct + (size_t)m*ZPAD + e0);
  bf16x8 yv = *(const bf16x8*)(y + (size_t)m*D_INNER + e0);
  float v[8]; float ss = 0.f;
  #pragma unroll
  for (int j=0;j<8;j++){
    float val = (float)yv[j] * fsilu((float)zv[j]);
    v[j] = val; ss += val*val;
  }
  #pragma unroll
  for (int off=32; off>0; off>>=1) ss += __shfl_down(ss, off, 64);
  __shared__ float red[4];
  if ((threadIdx.x & 63) == 0) red[threadIdx.x >> 6] = ss;
  __syncthreads();
  float tot = red[0]+red[1]+red[2]+red[3];
  float r = rsqrtf(tot * (1.f/D_INNER) + 1e-5f);
  bf16x8 o;
  #pragma unroll
  for (int j=0;j<8;j++) o[j] = (__bf16)(v[j] * r);
  *(bf16x8*)(y + (size_t)m*D_INNER + e0) = o;
}

extern "C" void kernel_launch(void* const* d_in, const int* in_sizes, int n_in,
                              void* d_out, int out_size, void* d_ws, size_t ws_size,
                              hipStream_t stream) {
  const float* u         = (const float*)d_in[0];
  const float* in_proj_w = (const float*)d_in[1];
  const float* conv_w    = (const float*)d_in[2];
  const float* conv_b    = (const float*)d_in[3];
  const float* dt_bias   = (const float*)d_in[4];
  const float* A_log     = (const float*)d_in[5];
  const float* Dp        = (const float*)d_in[6];
  const float* norm_w    = (const float*)d_in[7];
  const float* out_proj_w= (const float*)d_in[8];
  float* out = (float*)d_out;

  char* p = (char*)d_ws;
  auto alloc = [&](size_t bytes){ char* r = p; p += (bytes + 255) & ~size_t(255); return r; };
  bf16*  zxbct = (bf16*) alloc((size_t)MROWS*ZPAD*2);                    //  71.3 MB
  bf16*  xbc   = (bf16*) alloc((size_t)MROWS*CONV_DIM*2);                //  35.7 MB
  bf16*  y     = (bf16*) alloc((size_t)MROWS*D_INNER*2);                 //  33.6 MB
  bf16*  ub    = (bf16*) alloc((size_t)MROWS*D_MODEL*2);                 //  16.8 MB (alias: states)
  bf16*  Wb_in = (bf16*) alloc((size_t)ZPAD*D_MODEL*2);                  //   8.9 MB (alias: prevb)
  bf16*  Wb_out= (bf16*) alloc((size_t)D_MODEL*D_INNER*2);               //   4.2 MB
  float* dt_t  = (float*)alloc((size_t)NB*NHEADS*LEN*4);                 //   0.5 MB
  float* acum_t= (float*)alloc((size_t)NB*NHEADS*LEN*4);                 //   0.5 MB
  float* cd_t  = (float*)alloc((size_t)NB*NHEADS*NC*4);                  //   tiny
  float* states= (float*)ub;     // 16.8 MB, live after in_proj GEMM
  bf16*  prevb = (bf16*)Wb_in;   //  8.4 MB, live after in_proj GEMM
  // total ~171.5 MB

  dim3 blk(256);
  k_convert<<<dim3((NU4+NW14+NW24)/256), blk, 0, stream>>>(
      u, in_proj_w, out_proj_w, norm_w, ub, Wb_in, Wb_out);

  k_gemm_mfma<bf16><<<dim3(MROWS/128, ZPAD/128), blk, 0, stream>>>(
      ub, D_MODEL, Wb_in, D_MODEL, zxbct, ZPAD, D_MODEL);

  k_dt    <<<dim3(NB*NC*NHEADS), blk, 0, stream>>>(zxbct, dt_bias, A_log, dt_t, acum_t, cd_t);
  k_conv  <<<dim3(CONV_DIM/64, MROWS/64), blk, 0, stream>>>(zxbct, conv_w, conv_b, xbc);
  k_states<<<dim3(NB*NC*NHEADS), blk, 0, stream>>>(xbc, acum_t, dt_t, states);
  k_scan  <<<dim3(NB*NHEADS, 8), blk, 0, stream>>>(states, cd_t, prevb);
  k_fused <<<dim3(NB*NC*NHEADS), blk, 0, stream>>>(xbc, acum_t, dt_t, Dp, prevb, y);
  k_gatenorm<<<dim3(MROWS), blk, 0, stream>>>(zxbct, y);

  k_gemm_mfma<float><<<dim3(MROWS/128, D_MODEL/128), blk, 0, stream>>>(
      y, D_INNER, Wb_out, D_INNER, out, D_MODEL, D_INNER);
}